// Round 4
// baseline (877.266 us; speedup 1.0000x reference)
//
#include <hip/hip_runtime.h>
#include <math.h>

// Problem constants (fixed by reference: B=2, N=2048, d_model=1024, H=16, D=64)
#define SEQ   2048
#define DM    1024
#define NTOK  4096      // B*SEQ
#define HEADS 16
#define HDIM  64
#define ROPE_SCALE 0.006135923151542565f   // 2*pi/1024
#define L2_10000   13.287712379549449f     // log2(10000)

typedef __attribute__((ext_vector_type(8))) short bf16x8;
typedef __attribute__((ext_vector_type(4))) float f32x4;

__device__ __forceinline__ unsigned short f2bf(float f) {
    unsigned int u = __float_as_uint(f);
    return (unsigned short)((u + 0x7FFFu + ((u >> 16) & 1u)) >> 16);
}
__device__ __forceinline__ float bf2f(unsigned short h) {
    return __uint_as_float(((unsigned int)h) << 16);
}

__device__ __forceinline__ void split8(const float* __restrict__ src, bf16x8& h, bf16x8& l) {
    float4 f0 = ((const float4*)src)[0];
    float4 f1 = ((const float4*)src)[1];
    float fv[8] = {f0.x,f0.y,f0.z,f0.w,f1.x,f1.y,f1.z,f1.w};
    #pragma unroll
    for (int j = 0; j < 8; ++j) {
        unsigned short hb = f2bf(fv[j]);
        h[j] = (short)hb;
        l[j] = (short)f2bf(fv[j] - bf2f(hb));
    }
}

__device__ __forceinline__ void gload16(const void* g, void* l) {
    __builtin_amdgcn_global_load_lds(
        (const __attribute__((address_space(1))) unsigned int*)g,
        (__attribute__((address_space(3))) unsigned int*)l, 16, 0, 0);
}

// ---------------------------------------------------------------------------
// Pack fp32 [R][1024] -> swizzled bf16 hi|lo tiles of 128 rows x 32 k.
// Tile (mt,kt) is 16384 B at (mt*32+kt)*8192 shorts. In-tile byte offset of
// (r,k,part p) = (r*128 + p*64 + k*2) ^ ((r&7)<<4).
// ---------------------------------------------------------------------------
__global__ __launch_bounds__(256) void pack_swz(
    const float* __restrict__ src, unsigned short* __restrict__ dst)
{
    const int idx = blockIdx.x*256 + threadIdx.x;   // one thread per 8 elements
    const int e = idx * 8;
    const int r = e >> 10, k0 = e & 1023;
    bf16x8 h, l;
    split8(src + (size_t)r*DM + k0, h, l);
    const int mt = r >> 7, rl = r & 127;
    const int kt = k0 >> 5, kl = k0 & 31;
    char* tb = (char*)(dst + ((size_t)(mt*32 + kt))*8192);
    const int sw = (rl & 7) << 4;
    *(bf16x8*)(tb + ((rl*128 + kl*2) ^ sw))      = h;
    *(bf16x8*)(tb + ((rl*128 + 64 + kl*2) ^ sw)) = l;
}

// Fused [Wq;Wk;Wv] variant: rows 0..3071, source row (r&1023) of W[r>>10].
__global__ __launch_bounds__(256) void pack_swz3(
    const float* __restrict__ Wq, const float* __restrict__ Wk,
    const float* __restrict__ Wv, unsigned short* __restrict__ dst)
{
    const int idx = blockIdx.x*256 + threadIdx.x;
    const int e = idx * 8;
    const int r = e >> 10, k0 = e & 1023;
    const int proj = r >> 10;
    const float* W = proj==0 ? Wq : (proj==1 ? Wk : Wv);
    bf16x8 h, l;
    split8(W + (size_t)(r & 1023)*DM + k0, h, l);
    const int mt = r >> 7, rl = r & 127;
    const int kt = k0 >> 5, kl = k0 & 31;
    char* tb = (char*)(dst + ((size_t)(mt*32 + kt))*8192);
    const int sw = (rl & 7) << 4;
    *(bf16x8*)(tb + ((rl*128 + kl*2) ^ sw))      = h;
    *(bf16x8*)(tb + ((rl*128 + 64 + kl*2) ^ sw)) = l;
}

// ---------------------------------------------------------------------------
// Split-bf16 MFMA GEMM: C[M][N] = A[M][1024] @ B[N][1024]^T (+bias/epilogue).
// 256x256 block tile, BK=32, 8 waves (2x4), each wave 128x64 (8x4 frags),
// 3 MFMAs per product (hh+hl+lh). Double-buffered 128 KB LDS,
// global_load_lds staging (waves 0-3 stage A, 4-7 stage B).
// mode 0: fused qkv (N=3072): bias + 2D RoPE (q,k), scatter to [B][H][N][D].
// mode 1: out-proj (N=1024): bias, row-major [tok][1024].
// ---------------------------------------------------------------------------
__global__ __launch_bounds__(512, 2) void gemm_mfma(
    const unsigned short* __restrict__ Ap, const unsigned short* __restrict__ Bp,
    const int mode,
    const float* __restrict__ bq, const float* __restrict__ bk,
    const float* __restrict__ bv,
    const float* __restrict__ qpos, const float* __restrict__ kpos,
    float* __restrict__ qo, float* __restrict__ ko, float* __restrict__ vo,
    const float* __restrict__ bo, float* __restrict__ outp)
{
    __shared__ __align__(16) unsigned short Ab[2][16384];   // 2 x 32 KB
    __shared__ __align__(16) unsigned short Bb[2][16384];   // 2 x 32 KB

    const int tid = threadIdx.x, lane = tid & 63, wv = tid >> 6;
    const int col = lane & 15, grp = lane >> 4;
    const int wr = wv >> 2, wc = wv & 3;     // 2 x 4 wave grid
    const int mt = blockIdx.y, nt = blockIdx.x;

    f32x4 acc[8][4];
    #pragma unroll
    for (int mf=0; mf<8; ++mf)
        #pragma unroll
        for (int nf=0; nf<4; ++nf)
            acc[mf][nf] = (f32x4)0.f;

    auto stage = [&](int buf, int kt) {
        #pragma unroll
        for (int rep = 0; rep < 8; ++rep) {
            const int off = wv*8192 + rep*1024;          // 0..64K-1 across waves
            if (off < 32768) {                           // A half (waves 0-3)
                const int th = off >> 14, inner = off & 16383;
                const char* g = (const char*)Ap
                    + ((size_t)((mt*2 + th)*32 + kt))*16384 + inner;
                gload16(g + lane*16, (char*)&Ab[buf][0] + off);
            } else {                                     // B half (waves 4-7)
                const int o2 = off - 32768;
                const int th = o2 >> 14, inner = o2 & 16383;
                const char* g = (const char*)Bp
                    + ((size_t)((nt*2 + th)*32 + kt))*16384 + inner;
                gload16(g + lane*16, (char*)&Bb[buf][0] + o2);
            }
        }
    };

    stage(0, 0);
    int cur = 0;
    for (int kt = 0; kt < 32; ++kt) {
        __syncthreads();                       // drains vmcnt: buf[cur] ready
        if (kt < 31) stage(cur ^ 1, kt + 1);   // async prefetch next K-tile
        const char* A = (const char*)&Ab[cur][0];
        const char* B = (const char*)&Bb[cur][0];
        bf16x8 ah[8], al[8];
        #pragma unroll
        for (int mf = 0; mf < 8; ++mf) {
            const int rl = wr*128 + mf*16 + col;
            const int th = rl >> 7, r7 = rl & 127;
            const int b0 = r7*128 + grp*16;
            const int sw = (r7 & 7) << 4;
            const char* base = A + th*16384;
            ah[mf] = *(const bf16x8*)(base + (b0 ^ sw));
            al[mf] = *(const bf16x8*)(base + ((b0 + 64) ^ sw));
        }
        #pragma unroll
        for (int nf = 0; nf < 4; ++nf) {
            const int rl = wc*64 + nf*16 + col;
            const int th = rl >> 7, r7 = rl & 127;
            const int b0 = r7*128 + grp*16;
            const int sw = (r7 & 7) << 4;
            const char* base = B + th*16384;
            bf16x8 bh  = *(const bf16x8*)(base + (b0 ^ sw));
            bf16x8 blo = *(const bf16x8*)(base + ((b0 + 64) ^ sw));
            #pragma unroll
            for (int mf = 0; mf < 8; ++mf) {
                acc[mf][nf] = __builtin_amdgcn_mfma_f32_16x16x32_bf16(ah[mf], bh,  acc[mf][nf], 0,0,0);
                acc[mf][nf] = __builtin_amdgcn_mfma_f32_16x16x32_bf16(ah[mf], blo, acc[mf][nf], 0,0,0);
                acc[mf][nf] = __builtin_amdgcn_mfma_f32_16x16x32_bf16(al[mf], bh,  acc[mf][nf], 0,0,0);
            }
        }
        cur ^= 1;
    }

    // ---- epilogue. C row = mt*256+wr*128+mf*16+grp*4+i ; col = nt*256+wc*64+nf*16+col
    const int m0 = mt*256, n0 = nt*256;
    if (mode == 1) {
        #pragma unroll
        for (int nf = 0; nf < 4; ++nf) {
            const int n = n0 + wc*64 + nf*16 + col;
            const float bn = bo[n];
            #pragma unroll
            for (int mf = 0; mf < 8; ++mf)
                #pragma unroll
                for (int i = 0; i < 4; ++i) {
                    const int tok = m0 + wr*128 + mf*16 + grp*4 + i;
                    outp[(size_t)tok*DM + n] = acc[mf][nf][i] + bn;
                }
        }
    } else {
        const int proj = n0 >> 10;              // whole block is one projection
        const float* bb = proj==0 ? bq : (proj==1 ? bk : bv);
        float* op       = proj==0 ? qo : (proj==1 ? ko : vo);
        const float* pp = proj==0 ? qpos : kpos;
        #pragma unroll
        for (int nf = 0; nf < 4; ++nf) {
            const int n  = n0 + wc*64 + nf*16 + col;
            const int nn = n & 1023;
            const int h  = nn >> 6, dd = nn & 63;
            const float bn = bb[nn];
            if (proj == 2) {
                #pragma unroll
                for (int mf = 0; mf < 8; ++mf)
                    #pragma unroll
                    for (int i = 0; i < 4; ++i) {
                        const int tok = m0 + wr*128 + mf*16 + grp*4 + i;
                        const int b = tok >> 11, sq = tok & 2047;
                        op[(((size_t)(b*HEADS + h))*SEQ + sq)*HDIM + dd] = acc[mf][nf][i] + bn;
                    }
            } else {
                const int plane = dd >> 5;
                const float e = (float)(dd & 30) * (1.0f/32.0f);
                const float invf = exp2f(-L2_10000 * e);
                #pragma unroll
                for (int mf = 0; mf < 8; ++mf)
                    #pragma unroll
                    for (int i = 0; i < 4; ++i) {
                        const int tok = m0 + wr*128 + mf*16 + grp*4 + i;
                        const int b = tok >> 11, sq = tok & 2047;
                        const float pv = pp[((size_t)(b*SEQ + sq))*2 + plane];
                        const float ang = pv * ROPE_SCALE * invf;
                        float s, c;
                        sincosf(ang, &s, &c);
                        const float val = acc[mf][nf][i] + bn;
                        const float prt = __shfl_xor(val, 1);
                        const float res = (dd & 1) ? (prt*s + val*c) : (val*c - prt*s);
                        op[(((size_t)(b*HEADS + h))*SEQ + sq)*HDIM + dd] = res;
                    }
            }
        }
    }
}

// ---------------------------------------------------------------------------
// Kernel: MFMA flash attention (unchanged).
// ---------------------------------------------------------------------------
#define KB 32

__global__ __launch_bounds__(256) void attn_mfma(
    const float* __restrict__ q, const float* __restrict__ k,
    const float* __restrict__ v, float* __restrict__ ao)
{
    const int bh  = blockIdx.y;
    const int qb0 = blockIdx.x * 128;
    const int tid = threadIdx.x;
    const int lane = tid & 63;
    const int wv   = tid >> 6;
    const int col  = lane & 15;
    const int grp  = lane >> 4;

    __shared__ __align__(16) unsigned short Khi[KB][72];
    __shared__ __align__(16) unsigned short Klo[KB][72];
    __shared__ __align__(16) unsigned short Vthi[HDIM][40];
    __shared__ __align__(16) unsigned short Vtlo[HDIM][40];
    __shared__ __align__(16) unsigned short Pb[4][32][40];

    const float* kbase = k + (size_t)bh*SEQ*HDIM;
    const float* vbase = v + (size_t)bh*SEQ*HDIM;

    bf16x8 qhi[2][2], qlo[2][2];
    #pragma unroll
    for (int mf = 0; mf < 2; ++mf)
        #pragma unroll
        for (int ks = 0; ks < 2; ++ks) {
            const float* p = q + ((size_t)bh*SEQ + qb0 + wv*32 + mf*16 + col)*HDIM
                               + ks*32 + grp*8;
            split8(p, qhi[mf][ks], qlo[mf][ks]);
        }

    f32x4 o[2][4];
    #pragma unroll
    for (int mf=0; mf<2; ++mf)
        #pragma unroll
        for (int nf=0; nf<4; ++nf)
            o[mf][nf] = (f32x4)0.f;
    float mrun[2][4], lrun[2][4];
    #pragma unroll
    for (int mf=0; mf<2; ++mf)
        #pragma unroll
        for (int r=0; r<4; ++r) { mrun[mf][r] = -INFINITY; lrun[mf][r] = 0.f; }

    for (int kt = 0; kt < SEQ; kt += KB) {
        __syncthreads();
        {
            const int row = tid >> 3, c0 = (tid & 7) * 8;
            bf16x8 h, l;
            split8(kbase + (size_t)(kt + row)*HDIM + c0, h, l);
            *(bf16x8*)&Khi[row][c0] = h;
            *(bf16x8*)&Klo[row][c0] = l;
        }
        {
            const int key = tid & 31, db = tid >> 5;
            const float* src = vbase + (size_t)(kt + key)*HDIM + db*8;
            float4 f0 = ((const float4*)src)[0];
            float4 f1 = ((const float4*)src)[1];
            float fv[8] = {f0.x,f0.y,f0.z,f0.w,f1.x,f1.y,f1.z,f1.w};
            #pragma unroll
            for (int j = 0; j < 8; ++j) {
                unsigned short hb = f2bf(fv[j]);
                Vthi[db*8+j][key] = hb;
                Vtlo[db*8+j][key] = f2bf(fv[j] - bf2f(hb));
            }
        }
        __syncthreads();

        f32x4 s[2][2];
        #pragma unroll
        for (int mf=0; mf<2; ++mf)
            #pragma unroll
            for (int nf=0; nf<2; ++nf)
                s[mf][nf] = (f32x4)0.f;
        #pragma unroll
        for (int ks = 0; ks < 2; ++ks) {
            bf16x8 kh[2], kl[2];
            #pragma unroll
            for (int nf = 0; nf < 2; ++nf) {
                kh[nf] = *(const bf16x8*)&Khi[nf*16 + col][ks*32 + grp*8];
                kl[nf] = *(const bf16x8*)&Klo[nf*16 + col][ks*32 + grp*8];
            }
            #pragma unroll
            for (int mf = 0; mf < 2; ++mf)
                #pragma unroll
                for (int nf = 0; nf < 2; ++nf) {
                    s[mf][nf] = __builtin_amdgcn_mfma_f32_16x16x32_bf16(qhi[mf][ks], kh[nf], s[mf][nf], 0,0,0);
                    s[mf][nf] = __builtin_amdgcn_mfma_f32_16x16x32_bf16(qlo[mf][ks], kh[nf], s[mf][nf], 0,0,0);
                    s[mf][nf] = __builtin_amdgcn_mfma_f32_16x16x32_bf16(qhi[mf][ks], kl[nf], s[mf][nf], 0,0,0);
                }
        }

        #pragma unroll
        for (int mf=0; mf<2; ++mf)
            #pragma unroll
            for (int nf=0; nf<2; ++nf)
                s[mf][nf] *= 0.125f;

        #pragma unroll
        for (int mf = 0; mf < 2; ++mf) {
            #pragma unroll
            for (int r = 0; r < 4; ++r) {
                float m2 = fmaxf(s[mf][0][r], s[mf][1][r]);
                m2 = fmaxf(m2, __shfl_xor(m2, 1, 16));
                m2 = fmaxf(m2, __shfl_xor(m2, 2, 16));
                m2 = fmaxf(m2, __shfl_xor(m2, 4, 16));
                m2 = fmaxf(m2, __shfl_xor(m2, 8, 16));
                const float mnew = fmaxf(mrun[mf][r], m2);
                const float corr = __expf(mrun[mf][r] - mnew);
                mrun[mf][r] = mnew;
                const float p0 = __expf(s[mf][0][r] - mnew);
                const float p1 = __expf(s[mf][1][r] - mnew);
                float ts = p0 + p1;
                ts += __shfl_xor(ts, 1, 16);
                ts += __shfl_xor(ts, 2, 16);
                ts += __shfl_xor(ts, 4, 16);
                ts += __shfl_xor(ts, 8, 16);
                lrun[mf][r] = lrun[mf][r]*corr + ts;
                #pragma unroll
                for (int nf=0; nf<4; ++nf) o[mf][nf][r] *= corr;
                Pb[wv][mf*16 + grp*4 + r][col]      = f2bf(p0);
                Pb[wv][mf*16 + grp*4 + r][16 + col] = f2bf(p1);
            }
        }

        bf16x8 pa[2];
        #pragma unroll
        for (int mf=0; mf<2; ++mf)
            pa[mf] = *(const bf16x8*)&Pb[wv][mf*16 + col][grp*8];
        #pragma unroll
        for (int nf = 0; nf < 4; ++nf) {
            bf16x8 vh = *(const bf16x8*)&Vthi[nf*16 + col][grp*8];
            bf16x8 vl = *(const bf16x8*)&Vtlo[nf*16 + col][grp*8];
            #pragma unroll
            for (int mf = 0; mf < 2; ++mf) {
                o[mf][nf] = __builtin_amdgcn_mfma_f32_16x16x32_bf16(pa[mf], vh, o[mf][nf], 0,0,0);
                o[mf][nf] = __builtin_amdgcn_mfma_f32_16x16x32_bf16(pa[mf], vl, o[mf][nf], 0,0,0);
            }
        }
    }

    const int b = bh >> 4, h = bh & 15;
    #pragma unroll
    for (int mf = 0; mf < 2; ++mf)
        #pragma unroll
        for (int r = 0; r < 4; ++r) {
            const float inv = 1.0f / lrun[mf][r];
            const int n = qb0 + wv*32 + mf*16 + grp*4 + r;
            float* orow = ao + (((size_t)b*SEQ + n)*HEADS + h)*HDIM;
            #pragma unroll
            for (int nf = 0; nf < 4; ++nf)
                orow[nf*16 + col] = o[mf][nf][r] * inv;
        }
}

// ---------------------------------------------------------------------------
extern "C" void kernel_launch(void* const* d_in, const int* in_sizes, int n_in,
                              void* d_out, int out_size, void* d_ws, size_t ws_size,
                              hipStream_t stream)
{
    const float* x    = (const float*)d_in[0];
    const float* qpos = (const float*)d_in[1];
    const float* kpos = (const float*)d_in[2];
    const float* Wq   = (const float*)d_in[3];
    const float* bq   = (const float*)d_in[4];
    const float* Wk   = (const float*)d_in[5];
    const float* bk   = (const float*)d_in[6];
    const float* Wv   = (const float*)d_in[7];
    const float* bv   = (const float*)d_in[8];
    const float* Wo   = (const float*)d_in[9];
    const float* bo   = (const float*)d_in[10];
    float* out = (float*)d_out;

    // workspace (80 MB):
    //   qw/kw/vw fp32 [B*H][N][D]                       48 MB
    //   Xp   packed X (also reused for packed attn-out) 16 MB
    //   Wqkvp packed [Wq;Wk;Wv]                         12 MB
    //   Wop  packed Wo                                   4 MB
    float* qw = (float*)d_ws;
    float* kw = qw + (size_t)NTOK*DM;
    float* vw = kw + (size_t)NTOK*DM;
    unsigned short* Xp    = (unsigned short*)(vw + (size_t)NTOK*DM);
    unsigned short* Wqkvp = Xp + (size_t)NTOK*DM*2;
    unsigned short* Wop   = Wqkvp + (size_t)3*DM*DM*2;

    pack_swz <<<2048, 256, 0, stream>>>(x, Xp);
    pack_swz3<<<1536, 256, 0, stream>>>(Wq, Wk, Wv, Wqkvp);
    pack_swz <<< 512, 256, 0, stream>>>(Wo, Wop);

    gemm_mfma<<<dim3(12, 16), 512, 0, stream>>>(
        Xp, Wqkvp, 0, bq, bk, bv, qpos, kpos, qw, kw, vw, nullptr, nullptr);

    attn_mfma<<<dim3(SEQ/128, 2*HEADS), 256, 0, stream>>>(qw, kw, vw, out);

    pack_swz <<<2048, 256, 0, stream>>>(out, Xp);

    gemm_mfma<<<dim3(4, 16), 512, 0, stream>>>(
        Xp, Wop, 1, nullptr, nullptr, nullptr, nullptr, nullptr,
        nullptr, nullptr, nullptr, bo, out);
}

// Round 5
// 855.942 us; speedup vs baseline: 1.0249x; 1.0249x over previous
//
#include <hip/hip_runtime.h>
#include <math.h>

// Problem constants (fixed by reference: B=2, N=2048, d_model=1024, H=16, D=64)
#define SEQ   2048
#define DM    1024
#define NTOK  4096      // B*SEQ
#define HEADS 16
#define HDIM  64
#define ROPE_SCALE 0.006135923151542565f   // 2*pi/1024
#define L2_10000   13.287712379549449f     // log2(10000)

typedef __attribute__((ext_vector_type(8))) short bf16x8;
typedef __attribute__((ext_vector_type(4))) float f32x4;

__device__ __forceinline__ unsigned short f2bf(float f) {
    unsigned int u = __float_as_uint(f);
    return (unsigned short)((u + 0x7FFFu + ((u >> 16) & 1u)) >> 16);
}
__device__ __forceinline__ float bf2f(unsigned short h) {
    return __uint_as_float(((unsigned int)h) << 16);
}

__device__ __forceinline__ void split8(const float* __restrict__ src, bf16x8& h, bf16x8& l) {
    float4 f0 = ((const float4*)src)[0];
    float4 f1 = ((const float4*)src)[1];
    float fv[8] = {f0.x,f0.y,f0.z,f0.w,f1.x,f1.y,f1.z,f1.w};
    #pragma unroll
    for (int j = 0; j < 8; ++j) {
        unsigned short hb = f2bf(fv[j]);
        h[j] = (short)hb;
        l[j] = (short)f2bf(fv[j] - bf2f(hb));
    }
}

// ---------------------------------------------------------------------------
// Pack fp32 [R][1024] -> swizzled bf16 hi|lo tiles of 128 rows x 32 k.
// Tile (mt,kt) is 16384 B at (mt*32+kt)*8192 shorts. In-tile byte offset of
// (r,k,part p) = (r*128 + p*64 + k*2) ^ ((r&7)<<4).
// ---------------------------------------------------------------------------
__global__ __launch_bounds__(256) void pack_swz(
    const float* __restrict__ src, unsigned short* __restrict__ dst)
{
    const int idx = blockIdx.x*256 + threadIdx.x;   // one thread per 8 elements
    const int e = idx * 8;
    const int r = e >> 10, k0 = e & 1023;
    bf16x8 h, l;
    split8(src + (size_t)r*DM + k0, h, l);
    const int mt = r >> 7, rl = r & 127;
    const int kt = k0 >> 5, kl = k0 & 31;
    char* tb = (char*)(dst + ((size_t)(mt*32 + kt))*8192);
    const int sw = (rl & 7) << 4;
    *(bf16x8*)(tb + ((rl*128 + kl*2) ^ sw))      = h;
    *(bf16x8*)(tb + ((rl*128 + 64 + kl*2) ^ sw)) = l;
}

// Fused [Wq;Wk;Wv] variant: rows 0..3071, source row (r&1023) of W[r>>10].
__global__ __launch_bounds__(256) void pack_swz3(
    const float* __restrict__ Wq, const float* __restrict__ Wk,
    const float* __restrict__ Wv, unsigned short* __restrict__ dst)
{
    const int idx = blockIdx.x*256 + threadIdx.x;
    const int e = idx * 8;
    const int r = e >> 10, k0 = e & 1023;
    const int proj = r >> 10;
    const float* W = proj==0 ? Wq : (proj==1 ? Wk : Wv);
    bf16x8 h, l;
    split8(W + (size_t)(r & 1023)*DM + k0, h, l);
    const int mt = r >> 7, rl = r & 127;
    const int kt = k0 >> 5, kl = k0 & 31;
    char* tb = (char*)(dst + ((size_t)(mt*32 + kt))*8192);
    const int sw = (rl & 7) << 4;
    *(bf16x8*)(tb + ((rl*128 + kl*2) ^ sw))      = h;
    *(bf16x8*)(tb + ((rl*128 + 64 + kl*2) ^ sw)) = l;
}

// ---------------------------------------------------------------------------
// Split-bf16 MFMA GEMM: C[M][N] = A[M][1024] @ B[N][1024]^T (+bias/epilogue).
// 128x128 block tile, BK=32, 4 waves (2x2), 4x4 16x16 frags/wave, 3 MFMAs
// per product (hh+hl+lh). Double-buffered LDS; REGISTER-staged
// (global_load_dwordx4 -> ds_write_b128), 2-deep prefetch, named reg sets.
// mode 0: fused qkv (N=3072): bias + 2D RoPE (q,k), scatter to [B][H][N][D].
// mode 1: out-proj (N=1024): bias, row-major [tok][1024].
// ---------------------------------------------------------------------------
__global__ __launch_bounds__(256) void gemm_mfma(
    const unsigned short* __restrict__ Ap, const unsigned short* __restrict__ Bp,
    const int mode,
    const float* __restrict__ bq, const float* __restrict__ bk,
    const float* __restrict__ bv,
    const float* __restrict__ qpos, const float* __restrict__ kpos,
    float* __restrict__ qo, float* __restrict__ ko, float* __restrict__ vo,
    const float* __restrict__ bo, float* __restrict__ outp)
{
    __shared__ __align__(16) unsigned short Ab[2][8192];
    __shared__ __align__(16) unsigned short Bb[2][8192];

    const int tid = threadIdx.x, lane = tid & 63, wv = tid >> 6;
    const int col = lane & 15, grp = lane >> 4;
    const int wr = wv >> 1, wc = wv & 1;
    const int mt = blockIdx.y, nt = blockIdx.x;

    f32x4 acc[4][4];
    #pragma unroll
    for (int mf=0; mf<4; ++mf)
        #pragma unroll
        for (int nf=0; nf<4; ++nf)
            acc[mf][nf] = (f32x4)0.f;

    // ---- register staging: each thread moves 4x16B of A and of B per K-step
    auto loadrefs = [&](int kt, float4* ra, float4* rb) {
        const char* ga = (const char*)Ap + ((size_t)(mt*32 + kt))*16384;
        const char* gb = (const char*)Bp + ((size_t)(nt*32 + kt))*16384;
        #pragma unroll
        for (int i = 0; i < 4; ++i) {
            ra[i] = *(const float4*)(ga + tid*16 + i*4096);
            rb[i] = *(const float4*)(gb + tid*16 + i*4096);
        }
    };
    auto dswrite = [&](int buf, const float4* ra, const float4* rb) {
        #pragma unroll
        for (int i = 0; i < 4; ++i) {
            *(float4*)((char*)&Ab[buf][0] + tid*16 + i*4096) = ra[i];
            *(float4*)((char*)&Bb[buf][0] + tid*16 + i*4096) = rb[i];
        }
    };
    auto compute = [&](const unsigned short* As_, const unsigned short* Bs_) {
        const char* A = (const char*)As_;
        const char* B = (const char*)Bs_;
        bf16x8 ah[4], al[4];
        #pragma unroll
        for (int mf = 0; mf < 4; ++mf) {
            const int rl = wr*64 + mf*16 + col;
            const int b0 = rl*128 + grp*16;
            const int sw = (rl & 7) << 4;
            ah[mf] = *(const bf16x8*)(A + (b0 ^ sw));
            al[mf] = *(const bf16x8*)(A + ((b0 + 64) ^ sw));
        }
        #pragma unroll
        for (int nf = 0; nf < 4; ++nf) {
            const int rl = wc*64 + nf*16 + col;
            const int b0 = rl*128 + grp*16;
            const int sw = (rl & 7) << 4;
            bf16x8 bh  = *(const bf16x8*)(B + (b0 ^ sw));
            bf16x8 blo = *(const bf16x8*)(B + ((b0 + 64) ^ sw));
            #pragma unroll
            for (int mf = 0; mf < 4; ++mf) {
                acc[mf][nf] = __builtin_amdgcn_mfma_f32_16x16x32_bf16(ah[mf], bh,  acc[mf][nf], 0,0,0);
                acc[mf][nf] = __builtin_amdgcn_mfma_f32_16x16x32_bf16(ah[mf], blo, acc[mf][nf], 0,0,0);
                acc[mf][nf] = __builtin_amdgcn_mfma_f32_16x16x32_bf16(al[mf], bh,  acc[mf][nf], 0,0,0);
            }
        }
    };

    float4 a0[4], b0[4], a1[4], b1[4];      // two named prefetch sets (no
    loadrefs(0, a0, b0);                    // runtime indexing -> no scratch)
    dswrite(0, a0, b0);
    loadrefs(1, a1, b1);

    for (int kt = 0; kt < 32; kt += 2) {
        // -- step kt: data in buf0; write kt+1 -> buf1; load kt+2 -> set0
        __syncthreads();
        if (kt + 1 < 32) dswrite(1, a1, b1);
        if (kt + 2 < 32) loadrefs(kt + 2, a0, b0);
        compute(&Ab[0][0], &Bb[0][0]);
        // -- step kt+1: data in buf1; write kt+2 -> buf0; load kt+3 -> set1
        __syncthreads();
        if (kt + 2 < 32) dswrite(0, a0, b0);
        if (kt + 3 < 32) loadrefs(kt + 3, a1, b1);
        compute(&Ab[1][0], &Bb[1][0]);
    }

    // ---- epilogue. C row = m0+wr*64+mf*16+grp*4+i ; C col = n0+wc*64+nf*16+col
    const int m0 = mt*128, n0 = nt*128;
    if (mode == 1) {
        #pragma unroll
        for (int nf = 0; nf < 4; ++nf) {
            const int n = n0 + wc*64 + nf*16 + col;
            const float bn = bo[n];
            #pragma unroll
            for (int mf = 0; mf < 4; ++mf)
                #pragma unroll
                for (int i = 0; i < 4; ++i) {
                    const int tok = m0 + wr*64 + mf*16 + grp*4 + i;
                    outp[(size_t)tok*DM + n] = acc[mf][nf][i] + bn;
                }
        }
    } else {
        const int proj = n0 >> 10;              // whole block is one projection
        const float* bb = proj==0 ? bq : (proj==1 ? bk : bv);
        float* op       = proj==0 ? qo : (proj==1 ? ko : vo);
        const float* pp = proj==0 ? qpos : kpos;
        #pragma unroll
        for (int nf = 0; nf < 4; ++nf) {
            const int n  = n0 + wc*64 + nf*16 + col;
            const int nn = n & 1023;
            const int h  = nn >> 6, dd = nn & 63;
            const float bn = bb[nn];
            if (proj == 2) {
                #pragma unroll
                for (int mf = 0; mf < 4; ++mf)
                    #pragma unroll
                    for (int i = 0; i < 4; ++i) {
                        const int tok = m0 + wr*64 + mf*16 + grp*4 + i;
                        const int b = tok >> 11, sq = tok & 2047;
                        op[(((size_t)(b*HEADS + h))*SEQ + sq)*HDIM + dd] = acc[mf][nf][i] + bn;
                    }
            } else {
                const int plane = dd >> 5;
                const float e = (float)(dd & 30) * (1.0f/32.0f);
                const float invf = exp2f(-L2_10000 * e);
                #pragma unroll
                for (int mf = 0; mf < 4; ++mf)
                    #pragma unroll
                    for (int i = 0; i < 4; ++i) {
                        const int tok = m0 + wr*64 + mf*16 + grp*4 + i;
                        const int b = tok >> 11, sq = tok & 2047;
                        const float pv = pp[((size_t)(b*SEQ + sq))*2 + plane];
                        const float ang = pv * ROPE_SCALE * invf;
                        float s, c;
                        sincosf(ang, &s, &c);
                        const float val = acc[mf][nf][i] + bn;
                        const float prt = __shfl_xor(val, 1);
                        const float res = (dd & 1) ? (prt*s + val*c) : (val*c - prt*s);
                        op[(((size_t)(b*HEADS + h))*SEQ + sq)*HDIM + dd] = res;
                    }
            }
        }
    }
}

// ---------------------------------------------------------------------------
// Kernel: MFMA flash attention (unchanged).
// ---------------------------------------------------------------------------
#define KB 32

__global__ __launch_bounds__(256) void attn_mfma(
    const float* __restrict__ q, const float* __restrict__ k,
    const float* __restrict__ v, float* __restrict__ ao)
{
    const int bh  = blockIdx.y;
    const int qb0 = blockIdx.x * 128;
    const int tid = threadIdx.x;
    const int lane = tid & 63;
    const int wv   = tid >> 6;
    const int col  = lane & 15;
    const int grp  = lane >> 4;

    __shared__ __align__(16) unsigned short Khi[KB][72];
    __shared__ __align__(16) unsigned short Klo[KB][72];
    __shared__ __align__(16) unsigned short Vthi[HDIM][40];
    __shared__ __align__(16) unsigned short Vtlo[HDIM][40];
    __shared__ __align__(16) unsigned short Pb[4][32][40];

    const float* kbase = k + (size_t)bh*SEQ*HDIM;
    const float* vbase = v + (size_t)bh*SEQ*HDIM;

    bf16x8 qhi[2][2], qlo[2][2];
    #pragma unroll
    for (int mf = 0; mf < 2; ++mf)
        #pragma unroll
        for (int ks = 0; ks < 2; ++ks) {
            const float* p = q + ((size_t)bh*SEQ + qb0 + wv*32 + mf*16 + col)*HDIM
                               + ks*32 + grp*8;
            split8(p, qhi[mf][ks], qlo[mf][ks]);
        }

    f32x4 o[2][4];
    #pragma unroll
    for (int mf=0; mf<2; ++mf)
        #pragma unroll
        for (int nf=0; nf<4; ++nf)
            o[mf][nf] = (f32x4)0.f;
    float mrun[2][4], lrun[2][4];
    #pragma unroll
    for (int mf=0; mf<2; ++mf)
        #pragma unroll
        for (int r=0; r<4; ++r) { mrun[mf][r] = -INFINITY; lrun[mf][r] = 0.f; }

    for (int kt = 0; kt < SEQ; kt += KB) {
        __syncthreads();
        {
            const int row = tid >> 3, c0 = (tid & 7) * 8;
            bf16x8 h, l;
            split8(kbase + (size_t)(kt + row)*HDIM + c0, h, l);
            *(bf16x8*)&Khi[row][c0] = h;
            *(bf16x8*)&Klo[row][c0] = l;
        }
        {
            const int key = tid & 31, db = tid >> 5;
            const float* src = vbase + (size_t)(kt + key)*HDIM + db*8;
            float4 f0 = ((const float4*)src)[0];
            float4 f1 = ((const float4*)src)[1];
            float fv[8] = {f0.x,f0.y,f0.z,f0.w,f1.x,f1.y,f1.z,f1.w};
            #pragma unroll
            for (int j = 0; j < 8; ++j) {
                unsigned short hb = f2bf(fv[j]);
                Vthi[db*8+j][key] = hb;
                Vtlo[db*8+j][key] = f2bf(fv[j] - bf2f(hb));
            }
        }
        __syncthreads();

        f32x4 s[2][2];
        #pragma unroll
        for (int mf=0; mf<2; ++mf)
            #pragma unroll
            for (int nf=0; nf<2; ++nf)
                s[mf][nf] = (f32x4)0.f;
        #pragma unroll
        for (int ks = 0; ks < 2; ++ks) {
            bf16x8 kh[2], kl[2];
            #pragma unroll
            for (int nf = 0; nf < 2; ++nf) {
                kh[nf] = *(const bf16x8*)&Khi[nf*16 + col][ks*32 + grp*8];
                kl[nf] = *(const bf16x8*)&Klo[nf*16 + col][ks*32 + grp*8];
            }
            #pragma unroll
            for (int mf = 0; mf < 2; ++mf)
                #pragma unroll
                for (int nf = 0; nf < 2; ++nf) {
                    s[mf][nf] = __builtin_amdgcn_mfma_f32_16x16x32_bf16(qhi[mf][ks], kh[nf], s[mf][nf], 0,0,0);
                    s[mf][nf] = __builtin_amdgcn_mfma_f32_16x16x32_bf16(qlo[mf][ks], kh[nf], s[mf][nf], 0,0,0);
                    s[mf][nf] = __builtin_amdgcn_mfma_f32_16x16x32_bf16(qhi[mf][ks], kl[nf], s[mf][nf], 0,0,0);
                }
        }

        #pragma unroll
        for (int mf=0; mf<2; ++mf)
            #pragma unroll
            for (int nf=0; nf<2; ++nf)
                s[mf][nf] *= 0.125f;

        #pragma unroll
        for (int mf = 0; mf < 2; ++mf) {
            #pragma unroll
            for (int r = 0; r < 4; ++r) {
                float m2 = fmaxf(s[mf][0][r], s[mf][1][r]);
                m2 = fmaxf(m2, __shfl_xor(m2, 1, 16));
                m2 = fmaxf(m2, __shfl_xor(m2, 2, 16));
                m2 = fmaxf(m2, __shfl_xor(m2, 4, 16));
                m2 = fmaxf(m2, __shfl_xor(m2, 8, 16));
                const float mnew = fmaxf(mrun[mf][r], m2);
                const float corr = __expf(mrun[mf][r] - mnew);
                mrun[mf][r] = mnew;
                const float p0 = __expf(s[mf][0][r] - mnew);
                const float p1 = __expf(s[mf][1][r] - mnew);
                float ts = p0 + p1;
                ts += __shfl_xor(ts, 1, 16);
                ts += __shfl_xor(ts, 2, 16);
                ts += __shfl_xor(ts, 4, 16);
                ts += __shfl_xor(ts, 8, 16);
                lrun[mf][r] = lrun[mf][r]*corr + ts;
                #pragma unroll
                for (int nf=0; nf<4; ++nf) o[mf][nf][r] *= corr;
                Pb[wv][mf*16 + grp*4 + r][col]      = f2bf(p0);
                Pb[wv][mf*16 + grp*4 + r][16 + col] = f2bf(p1);
            }
        }

        bf16x8 pa[2];
        #pragma unroll
        for (int mf=0; mf<2; ++mf)
            pa[mf] = *(const bf16x8*)&Pb[wv][mf*16 + col][grp*8];
        #pragma unroll
        for (int nf = 0; nf < 4; ++nf) {
            bf16x8 vh = *(const bf16x8*)&Vthi[nf*16 + col][grp*8];
            bf16x8 vl = *(const bf16x8*)&Vtlo[nf*16 + col][grp*8];
            #pragma unroll
            for (int mf = 0; mf < 2; ++mf) {
                o[mf][nf] = __builtin_amdgcn_mfma_f32_16x16x32_bf16(pa[mf], vh, o[mf][nf], 0,0,0);
                o[mf][nf] = __builtin_amdgcn_mfma_f32_16x16x32_bf16(pa[mf], vl, o[mf][nf], 0,0,0);
            }
        }
    }

    const int b = bh >> 4, h = bh & 15;
    #pragma unroll
    for (int mf = 0; mf < 2; ++mf)
        #pragma unroll
        for (int r = 0; r < 4; ++r) {
            const float inv = 1.0f / lrun[mf][r];
            const int n = qb0 + wv*32 + mf*16 + grp*4 + r;
            float* orow = ao + (((size_t)b*SEQ + n)*HEADS + h)*HDIM;
            #pragma unroll
            for (int nf = 0; nf < 4; ++nf)
                orow[nf*16 + col] = o[mf][nf][r] * inv;
        }
}

// ---------------------------------------------------------------------------
extern "C" void kernel_launch(void* const* d_in, const int* in_sizes, int n_in,
                              void* d_out, int out_size, void* d_ws, size_t ws_size,
                              hipStream_t stream)
{
    const float* x    = (const float*)d_in[0];
    const float* qpos = (const float*)d_in[1];
    const float* kpos = (const float*)d_in[2];
    const float* Wq   = (const float*)d_in[3];
    const float* bq   = (const float*)d_in[4];
    const float* Wk   = (const float*)d_in[5];
    const float* bk   = (const float*)d_in[6];
    const float* Wv   = (const float*)d_in[7];
    const float* bv   = (const float*)d_in[8];
    const float* Wo   = (const float*)d_in[9];
    const float* bo   = (const float*)d_in[10];
    float* out = (float*)d_out;

    // workspace (80 MB):
    //   qw/kw/vw fp32 [B*H][N][D]                       48 MB
    //   Xp   packed X (also reused for packed attn-out) 16 MB
    //   Wqkvp packed [Wq;Wk;Wv]                         12 MB
    //   Wop  packed Wo                                   4 MB
    float* qw = (float*)d_ws;
    float* kw = qw + (size_t)NTOK*DM;
    float* vw = kw + (size_t)NTOK*DM;
    unsigned short* Xp    = (unsigned short*)(vw + (size_t)NTOK*DM);
    unsigned short* Wqkvp = Xp + (size_t)NTOK*DM*2;
    unsigned short* Wop   = Wqkvp + (size_t)3*DM*DM*2;

    pack_swz <<<2048, 256, 0, stream>>>(x, Xp);
    pack_swz3<<<1536, 256, 0, stream>>>(Wq, Wk, Wv, Wqkvp);
    pack_swz <<< 512, 256, 0, stream>>>(Wo, Wop);

    gemm_mfma<<<dim3(24, 32), 256, 0, stream>>>(
        Xp, Wqkvp, 0, bq, bk, bv, qpos, kpos, qw, kw, vw, nullptr, nullptr);

    attn_mfma<<<dim3(SEQ/128, 2*HEADS), 256, 0, stream>>>(qw, kw, vw, out);

    pack_swz <<<2048, 256, 0, stream>>>(out, Xp);

    gemm_mfma<<<dim3(8, 32), 256, 0, stream>>>(
        Xp, Wop, 1, nullptr, nullptr, nullptr, nullptr, nullptr,
        nullptr, nullptr, nullptr, bo, out);
}

// Round 6
// 671.104 us; speedup vs baseline: 1.3072x; 1.2754x over previous
//
#include <hip/hip_runtime.h>
#include <math.h>

// Problem constants (fixed by reference: B=2, N=2048, d_model=1024, H=16, D=64)
#define SEQ   2048
#define DM    1024
#define NTOK  4096      // B*SEQ
#define HEADS 16
#define HDIM  64
#define ROPE_SCALE 0.006135923151542565f   // 2*pi/1024
#define L2_10000   13.287712379549449f     // log2(10000)

typedef __attribute__((ext_vector_type(8))) short bf16x8;
typedef __attribute__((ext_vector_type(4))) float f32x4;

__device__ __forceinline__ unsigned short f2bf(float f) {
    unsigned int u = __float_as_uint(f);
    return (unsigned short)((u + 0x7FFFu + ((u >> 16) & 1u)) >> 16);
}
__device__ __forceinline__ float bf2f(unsigned short h) {
    return __uint_as_float(((unsigned int)h) << 16);
}

__device__ __forceinline__ void split8(const float* __restrict__ src, bf16x8& h, bf16x8& l) {
    float4 f0 = ((const float4*)src)[0];
    float4 f1 = ((const float4*)src)[1];
    float fv[8] = {f0.x,f0.y,f0.z,f0.w,f1.x,f1.y,f1.z,f1.w};
    #pragma unroll
    for (int j = 0; j < 8; ++j) {
        unsigned short hb = f2bf(fv[j]);
        h[j] = (short)hb;
        l[j] = (short)f2bf(fv[j] - bf2f(hb));
    }
}

__device__ __forceinline__ void gload16(const void* g, void* l) {
    __builtin_amdgcn_global_load_lds(
        (const __attribute__((address_space(1))) unsigned int*)g,
        (__attribute__((address_space(3))) unsigned int*)l, 16, 0, 0);
}

// ---------------------------------------------------------------------------
// Pack fp32 [R][1024] -> swizzled bf16 hi|lo tiles of 128 rows x 32 k.
// Tile (mt,kt) is 16384 B at (mt*32+kt)*8192 shorts. In-tile byte offset of
// (r,k,part p) = (r*128 + p*64 + k*2) ^ ((r&7)<<4).
// ---------------------------------------------------------------------------
__global__ __launch_bounds__(256) void pack_swz(
    const float* __restrict__ src, unsigned short* __restrict__ dst)
{
    const int idx = blockIdx.x*256 + threadIdx.x;   // one thread per 8 elements
    const int e = idx * 8;
    const int r = e >> 10, k0 = e & 1023;
    bf16x8 h, l;
    split8(src + (size_t)r*DM + k0, h, l);
    const int mt = r >> 7, rl = r & 127;
    const int kt = k0 >> 5, kl = k0 & 31;
    char* tb = (char*)(dst + ((size_t)(mt*32 + kt))*8192);
    const int sw = (rl & 7) << 4;
    *(bf16x8*)(tb + ((rl*128 + kl*2) ^ sw))      = h;
    *(bf16x8*)(tb + ((rl*128 + 64 + kl*2) ^ sw)) = l;
}

// Fused [Wq;Wk;Wv] variant: rows 0..3071, source row (r&1023) of W[r>>10].
__global__ __launch_bounds__(256) void pack_swz3(
    const float* __restrict__ Wq, const float* __restrict__ Wk,
    const float* __restrict__ Wv, unsigned short* __restrict__ dst)
{
    const int idx = blockIdx.x*256 + threadIdx.x;
    const int e = idx * 8;
    const int r = e >> 10, k0 = e & 1023;
    const int proj = r >> 10;
    const float* W = proj==0 ? Wq : (proj==1 ? Wk : Wv);
    bf16x8 h, l;
    split8(W + (size_t)(r & 1023)*DM + k0, h, l);
    const int mt = r >> 7, rl = r & 127;
    const int kt = k0 >> 5, kl = k0 & 31;
    char* tb = (char*)(dst + ((size_t)(mt*32 + kt))*8192);
    const int sw = (rl & 7) << 4;
    *(bf16x8*)(tb + ((rl*128 + kl*2) ^ sw))      = h;
    *(bf16x8*)(tb + ((rl*128 + 64 + kl*2) ^ sw)) = l;
}

// ---------------------------------------------------------------------------
// Split-bf16 MFMA GEMM: C[M][N] = A[M][1024] @ B[N][1024]^T (+bias/epilogue).
// 128x128 block tile, BK=32, 4 waves (2x2), 4x4 16x16 frags/wave, 3 MFMAs
// per product (hh+hl+lh). m97 schedule: SINGLE-buffered 32 KB LDS,
// 2 barriers per K-step, global_load_lds staging; cross-block overlap
// (~3 blocks/CU) hides the vmcnt drain. XCD-chunked block remap for
// A-panel L2 locality.
// mode 0: fused qkv (N=3072): bias + 2D RoPE (q,k), scatter to [B][H][N][D].
// mode 1: out-proj (N=1024): bias, row-major [tok][1024].
// ---------------------------------------------------------------------------
__global__ __launch_bounds__(256, 3) void gemm_mfma(
    const unsigned short* __restrict__ Ap, const unsigned short* __restrict__ Bp,
    const int mode,
    const float* __restrict__ bq, const float* __restrict__ bk,
    const float* __restrict__ bv,
    const float* __restrict__ qpos, const float* __restrict__ kpos,
    float* __restrict__ qo, float* __restrict__ ko, float* __restrict__ vo,
    const float* __restrict__ bo, float* __restrict__ outp)
{
    __shared__ __align__(16) unsigned short Ab[8192];   // 16 KB (hi|lo tile)
    __shared__ __align__(16) unsigned short Bb[8192];   // 16 KB

    const int tid = threadIdx.x, lane = tid & 63, wv = tid >> 6;
    const int col = lane & 15, grp = lane >> 4;
    const int wr = wv >> 1, wc = wv & 1;

    // XCD-bijective remap: all nt-blocks of an mt-panel group land on one XCD.
    const int NX = gridDim.x, NB = NX * gridDim.y;
    const int bid = blockIdx.y * NX + blockIdx.x;
    const int bid2 = (bid & 7) * (NB >> 3) + (bid >> 3);   // NB % 8 == 0
    const int nt = bid2 % NX, mt = bid2 / NX;

    f32x4 acc[4][4];
    #pragma unroll
    for (int mf=0; mf<4; ++mf)
        #pragma unroll
        for (int nf=0; nf<4; ++nf)
            acc[mf][nf] = (f32x4)0.f;

    for (int kt = 0; kt < 32; ++kt) {
        __syncthreads();     // previous step's readers done
        {   // stage 16 KB A + 16 KB B (linear; pre-swizzled in global)
            const char* ga = (const char*)Ap + ((size_t)(mt*32 + kt))*16384;
            const char* gb = (const char*)Bp + ((size_t)(nt*32 + kt))*16384;
            #pragma unroll
            for (int rep = 0; rep < 4; ++rep) {
                const int o = wv*4096 + rep*1024;
                gload16(ga + o + lane*16, (char*)Ab + o);
                gload16(gb + o + lane*16, (char*)Bb + o);
            }
        }
        __syncthreads();     // compiler drains vmcnt(0): tile ready
        const char* A = (const char*)Ab;
        const char* B = (const char*)Bb;
        bf16x8 ah[4], al[4];
        #pragma unroll
        for (int mf = 0; mf < 4; ++mf) {
            const int rl = wr*64 + mf*16 + col;
            const int b0 = rl*128 + grp*16;
            const int sw = (rl & 7) << 4;
            ah[mf] = *(const bf16x8*)(A + (b0 ^ sw));
            al[mf] = *(const bf16x8*)(A + ((b0 + 64) ^ sw));
        }
        #pragma unroll
        for (int nf = 0; nf < 4; ++nf) {
            const int rl = wc*64 + nf*16 + col;
            const int b0 = rl*128 + grp*16;
            const int sw = (rl & 7) << 4;
            bf16x8 bh  = *(const bf16x8*)(B + (b0 ^ sw));
            bf16x8 blo = *(const bf16x8*)(B + ((b0 + 64) ^ sw));
            #pragma unroll
            for (int mf = 0; mf < 4; ++mf) {
                acc[mf][nf] = __builtin_amdgcn_mfma_f32_16x16x32_bf16(ah[mf], bh,  acc[mf][nf], 0,0,0);
                acc[mf][nf] = __builtin_amdgcn_mfma_f32_16x16x32_bf16(ah[mf], blo, acc[mf][nf], 0,0,0);
                acc[mf][nf] = __builtin_amdgcn_mfma_f32_16x16x32_bf16(al[mf], bh,  acc[mf][nf], 0,0,0);
            }
        }
    }

    // ---- epilogue. C row = m0+wr*64+mf*16+grp*4+i ; C col = n0+wc*64+nf*16+col
    const int m0 = mt*128, n0 = nt*128;
    if (mode == 1) {
        #pragma unroll
        for (int nf = 0; nf < 4; ++nf) {
            const int n = n0 + wc*64 + nf*16 + col;
            const float bn = bo[n];
            #pragma unroll
            for (int mf = 0; mf < 4; ++mf)
                #pragma unroll
                for (int i = 0; i < 4; ++i) {
                    const int tok = m0 + wr*64 + mf*16 + grp*4 + i;
                    outp[(size_t)tok*DM + n] = acc[mf][nf][i] + bn;
                }
        }
    } else {
        const int proj = n0 >> 10;              // whole block is one projection
        const float* bb = proj==0 ? bq : (proj==1 ? bk : bv);
        float* op       = proj==0 ? qo : (proj==1 ? ko : vo);
        const float* pp = proj==0 ? qpos : kpos;
        #pragma unroll
        for (int nf = 0; nf < 4; ++nf) {
            const int n  = n0 + wc*64 + nf*16 + col;
            const int nn = n & 1023;
            const int h  = nn >> 6, dd = nn & 63;
            const float bn = bb[nn];
            if (proj == 2) {
                #pragma unroll
                for (int mf = 0; mf < 4; ++mf)
                    #pragma unroll
                    for (int i = 0; i < 4; ++i) {
                        const int tok = m0 + wr*64 + mf*16 + grp*4 + i;
                        const int b = tok >> 11, sq = tok & 2047;
                        op[(((size_t)(b*HEADS + h))*SEQ + sq)*HDIM + dd] = acc[mf][nf][i] + bn;
                    }
            } else {
                const int plane = dd >> 5;
                const float e = (float)(dd & 30) * (1.0f/32.0f);
                const float invf = exp2f(-L2_10000 * e);
                #pragma unroll
                for (int mf = 0; mf < 4; ++mf)
                    #pragma unroll
                    for (int i = 0; i < 4; ++i) {
                        const int tok = m0 + wr*64 + mf*16 + grp*4 + i;
                        const int b = tok >> 11, sq = tok & 2047;
                        const float pv = pp[((size_t)(b*SEQ + sq))*2 + plane];
                        const float ang = pv * ROPE_SCALE * invf;
                        float s, c;
                        sincosf(ang, &s, &c);
                        const float val = acc[mf][nf][i] + bn;
                        const float prt = __shfl_xor(val, 1);
                        const float res = (dd & 1) ? (prt*s + val*c) : (val*c - prt*s);
                        op[(((size_t)(b*HEADS + h))*SEQ + sq)*HDIM + dd] = res;
                    }
            }
        }
    }
}

// ---------------------------------------------------------------------------
// Kernel: MFMA flash attention (unchanged).
// ---------------------------------------------------------------------------
#define KB 32

__global__ __launch_bounds__(256) void attn_mfma(
    const float* __restrict__ q, const float* __restrict__ k,
    const float* __restrict__ v, float* __restrict__ ao)
{
    const int bh  = blockIdx.y;
    const int qb0 = blockIdx.x * 128;
    const int tid = threadIdx.x;
    const int lane = tid & 63;
    const int wv   = tid >> 6;
    const int col  = lane & 15;
    const int grp  = lane >> 4;

    __shared__ __align__(16) unsigned short Khi[KB][72];
    __shared__ __align__(16) unsigned short Klo[KB][72];
    __shared__ __align__(16) unsigned short Vthi[HDIM][40];
    __shared__ __align__(16) unsigned short Vtlo[HDIM][40];
    __shared__ __align__(16) unsigned short Pb[4][32][40];

    const float* kbase = k + (size_t)bh*SEQ*HDIM;
    const float* vbase = v + (size_t)bh*SEQ*HDIM;

    bf16x8 qhi[2][2], qlo[2][2];
    #pragma unroll
    for (int mf = 0; mf < 2; ++mf)
        #pragma unroll
        for (int ks = 0; ks < 2; ++ks) {
            const float* p = q + ((size_t)bh*SEQ + qb0 + wv*32 + mf*16 + col)*HDIM
                               + ks*32 + grp*8;
            split8(p, qhi[mf][ks], qlo[mf][ks]);
        }

    f32x4 o[2][4];
    #pragma unroll
    for (int mf=0; mf<2; ++mf)
        #pragma unroll
        for (int nf=0; nf<4; ++nf)
            o[mf][nf] = (f32x4)0.f;
    float mrun[2][4], lrun[2][4];
    #pragma unroll
    for (int mf=0; mf<2; ++mf)
        #pragma unroll
        for (int r=0; r<4; ++r) { mrun[mf][r] = -INFINITY; lrun[mf][r] = 0.f; }

    for (int kt = 0; kt < SEQ; kt += KB) {
        __syncthreads();
        {
            const int row = tid >> 3, c0 = (tid & 7) * 8;
            bf16x8 h, l;
            split8(kbase + (size_t)(kt + row)*HDIM + c0, h, l);
            *(bf16x8*)&Khi[row][c0] = h;
            *(bf16x8*)&Klo[row][c0] = l;
        }
        {
            const int key = tid & 31, db = tid >> 5;
            const float* src = vbase + (size_t)(kt + key)*HDIM + db*8;
            float4 f0 = ((const float4*)src)[0];
            float4 f1 = ((const float4*)src)[1];
            float fv[8] = {f0.x,f0.y,f0.z,f0.w,f1.x,f1.y,f1.z,f1.w};
            #pragma unroll
            for (int j = 0; j < 8; ++j) {
                unsigned short hb = f2bf(fv[j]);
                Vthi[db*8+j][key] = hb;
                Vtlo[db*8+j][key] = f2bf(fv[j] - bf2f(hb));
            }
        }
        __syncthreads();

        f32x4 s[2][2];
        #pragma unroll
        for (int mf=0; mf<2; ++mf)
            #pragma unroll
            for (int nf=0; nf<2; ++nf)
                s[mf][nf] = (f32x4)0.f;
        #pragma unroll
        for (int ks = 0; ks < 2; ++ks) {
            bf16x8 kh[2], kl[2];
            #pragma unroll
            for (int nf = 0; nf < 2; ++nf) {
                kh[nf] = *(const bf16x8*)&Khi[nf*16 + col][ks*32 + grp*8];
                kl[nf] = *(const bf16x8*)&Klo[nf*16 + col][ks*32 + grp*8];
            }
            #pragma unroll
            for (int mf = 0; mf < 2; ++mf)
                #pragma unroll
                for (int nf = 0; nf < 2; ++nf) {
                    s[mf][nf] = __builtin_amdgcn_mfma_f32_16x16x32_bf16(qhi[mf][ks], kh[nf], s[mf][nf], 0,0,0);
                    s[mf][nf] = __builtin_amdgcn_mfma_f32_16x16x32_bf16(qlo[mf][ks], kh[nf], s[mf][nf], 0,0,0);
                    s[mf][nf] = __builtin_amdgcn_mfma_f32_16x16x32_bf16(qhi[mf][ks], kl[nf], s[mf][nf], 0,0,0);
                }
        }

        #pragma unroll
        for (int mf=0; mf<2; ++mf)
            #pragma unroll
            for (int nf=0; nf<2; ++nf)
                s[mf][nf] *= 0.125f;

        #pragma unroll
        for (int mf = 0; mf < 2; ++mf) {
            #pragma unroll
            for (int r = 0; r < 4; ++r) {
                float m2 = fmaxf(s[mf][0][r], s[mf][1][r]);
                m2 = fmaxf(m2, __shfl_xor(m2, 1, 16));
                m2 = fmaxf(m2, __shfl_xor(m2, 2, 16));
                m2 = fmaxf(m2, __shfl_xor(m2, 4, 16));
                m2 = fmaxf(m2, __shfl_xor(m2, 8, 16));
                const float mnew = fmaxf(mrun[mf][r], m2);
                const float corr = __expf(mrun[mf][r] - mnew);
                mrun[mf][r] = mnew;
                const float p0 = __expf(s[mf][0][r] - mnew);
                const float p1 = __expf(s[mf][1][r] - mnew);
                float ts = p0 + p1;
                ts += __shfl_xor(ts, 1, 16);
                ts += __shfl_xor(ts, 2, 16);
                ts += __shfl_xor(ts, 4, 16);
                ts += __shfl_xor(ts, 8, 16);
                lrun[mf][r] = lrun[mf][r]*corr + ts;
                #pragma unroll
                for (int nf=0; nf<4; ++nf) o[mf][nf][r] *= corr;
                Pb[wv][mf*16 + grp*4 + r][col]      = f2bf(p0);
                Pb[wv][mf*16 + grp*4 + r][16 + col] = f2bf(p1);
            }
        }

        bf16x8 pa[2];
        #pragma unroll
        for (int mf=0; mf<2; ++mf)
            pa[mf] = *(const bf16x8*)&Pb[wv][mf*16 + col][grp*8];
        #pragma unroll
        for (int nf = 0; nf < 4; ++nf) {
            bf16x8 vh = *(const bf16x8*)&Vthi[nf*16 + col][grp*8];
            bf16x8 vl = *(const bf16x8*)&Vtlo[nf*16 + col][grp*8];
            #pragma unroll
            for (int mf = 0; mf < 2; ++mf) {
                o[mf][nf] = __builtin_amdgcn_mfma_f32_16x16x32_bf16(pa[mf], vh, o[mf][nf], 0,0,0);
                o[mf][nf] = __builtin_amdgcn_mfma_f32_16x16x32_bf16(pa[mf], vl, o[mf][nf], 0,0,0);
            }
        }
    }

    const int b = bh >> 4, h = bh & 15;
    #pragma unroll
    for (int mf = 0; mf < 2; ++mf)
        #pragma unroll
        for (int r = 0; r < 4; ++r) {
            const float inv = 1.0f / lrun[mf][r];
            const int n = qb0 + wv*32 + mf*16 + grp*4 + r;
            float* orow = ao + (((size_t)b*SEQ + n)*HEADS + h)*HDIM;
            #pragma unroll
            for (int nf = 0; nf < 4; ++nf)
                orow[nf*16 + col] = o[mf][nf][r] * inv;
        }
}

// ---------------------------------------------------------------------------
extern "C" void kernel_launch(void* const* d_in, const int* in_sizes, int n_in,
                              void* d_out, int out_size, void* d_ws, size_t ws_size,
                              hipStream_t stream)
{
    const float* x    = (const float*)d_in[0];
    const float* qpos = (const float*)d_in[1];
    const float* kpos = (const float*)d_in[2];
    const float* Wq   = (const float*)d_in[3];
    const float* bq   = (const float*)d_in[4];
    const float* Wk   = (const float*)d_in[5];
    const float* bk   = (const float*)d_in[6];
    const float* Wv   = (const float*)d_in[7];
    const float* bv   = (const float*)d_in[8];
    const float* Wo   = (const float*)d_in[9];
    const float* bo   = (const float*)d_in[10];
    float* out = (float*)d_out;

    // workspace (80 MB):
    //   qw/kw/vw fp32 [B*H][N][D]                       48 MB
    //   Xp   packed X (also reused for packed attn-out) 16 MB
    //   Wqkvp packed [Wq;Wk;Wv]                         12 MB
    //   Wop  packed Wo                                   4 MB
    float* qw = (float*)d_ws;
    float* kw = qw + (size_t)NTOK*DM;
    float* vw = kw + (size_t)NTOK*DM;
    unsigned short* Xp    = (unsigned short*)(vw + (size_t)NTOK*DM);
    unsigned short* Wqkvp = Xp + (size_t)NTOK*DM*2;
    unsigned short* Wop   = Wqkvp + (size_t)3*DM*DM*2;

    pack_swz <<<2048, 256, 0, stream>>>(x, Xp);
    pack_swz3<<<1536, 256, 0, stream>>>(Wq, Wk, Wv, Wqkvp);
    pack_swz <<< 512, 256, 0, stream>>>(Wo, Wop);

    gemm_mfma<<<dim3(24, 32), 256, 0, stream>>>(
        Xp, Wqkvp, 0, bq, bk, bv, qpos, kpos, qw, kw, vw, nullptr, nullptr);

    attn_mfma<<<dim3(SEQ/128, 2*HEADS), 256, 0, stream>>>(qw, kw, vw, out);

    pack_swz <<<2048, 256, 0, stream>>>(out, Xp);

    gemm_mfma<<<dim3(8, 32), 256, 0, stream>>>(
        Xp, Wop, 1, nullptr, nullptr, nullptr, nullptr, nullptr,
        nullptr, nullptr, nullptr, bo, out);
}

// Round 7
// 669.727 us; speedup vs baseline: 1.3099x; 1.0021x over previous
//
#include <hip/hip_runtime.h>
#include <math.h>

// Problem constants (fixed by reference: B=2, N=2048, d_model=1024, H=16, D=64)
#define SEQ   2048
#define DM    1024
#define NTOK  4096      // B*SEQ
#define HEADS 16
#define HDIM  64
#define ROPE_SCALE 0.006135923151542565f   // 2*pi/1024
#define L2_10000   13.287712379549449f     // log2(10000)

typedef __attribute__((ext_vector_type(8))) short bf16x8;
typedef __attribute__((ext_vector_type(4))) float f32x4;

__device__ __forceinline__ unsigned short f2bf(float f) {
    unsigned int u = __float_as_uint(f);
    return (unsigned short)((u + 0x7FFFu + ((u >> 16) & 1u)) >> 16);
}
__device__ __forceinline__ float bf2f(unsigned short h) {
    return __uint_as_float(((unsigned int)h) << 16);
}

__device__ __forceinline__ void split8(const float* __restrict__ src, bf16x8& h, bf16x8& l) {
    float4 f0 = ((const float4*)src)[0];
    float4 f1 = ((const float4*)src)[1];
    float fv[8] = {f0.x,f0.y,f0.z,f0.w,f1.x,f1.y,f1.z,f1.w};
    #pragma unroll
    for (int j = 0; j < 8; ++j) {
        unsigned short hb = f2bf(fv[j]);
        h[j] = (short)hb;
        l[j] = (short)f2bf(fv[j] - bf2f(hb));
    }
}

// pack top-16 bits of two fp32 into one u32 (bf16 pair, elem0 in low half)
__device__ __forceinline__ unsigned int packtop(unsigned int b0, unsigned int b1) {
    return (b1 & 0xffff0000u) | (b0 >> 16);
}

// ---------------------------------------------------------------------------
// Fused split-bf16 MFMA GEMM reading fp32 operands DIRECTLY (no packed
// intermediates): C[M][N] = A[M][1024] @ W[N][1024]^T (+bias/epilogue).
// 128x128 block tile, BK=32, 4 waves (2x2), 4x4 16x16 frags/wave, 3 MFMAs
// per product (hh+hl+lh). Truncation hi/lo split in-register during staging;
// ds_write_b128 to XOR-swizzled LDS; single-buffered 32 KB LDS, 2 barriers
// per K-step (m97 schedule); XCD-chunked block remap.
// LDS layout: byte (r*128 + p*64 + k*2) ^ ((r&7)<<4), p=0 hi / p=1 lo.
// mode 0: fused qkv (N=3072): bias + 2D RoPE (q,k), scatter to [B][H][N][D].
// mode 1: out-proj (N=1024): bias, row-major [tok][1024].
// ---------------------------------------------------------------------------
__global__ __launch_bounds__(256, 3) void gemm_fused(
    const float* __restrict__ A,
    const float* __restrict__ W0, const float* __restrict__ W1,
    const float* __restrict__ W2,
    const int mode,
    const float* __restrict__ bq, const float* __restrict__ bk,
    const float* __restrict__ bv,
    const float* __restrict__ qpos, const float* __restrict__ kpos,
    float* __restrict__ qo, float* __restrict__ ko, float* __restrict__ vo,
    const float* __restrict__ bo, float* __restrict__ outp)
{
    __shared__ __align__(16) unsigned short Ab[8192];   // 16 KB hi|lo
    __shared__ __align__(16) unsigned short Bb[8192];   // 16 KB hi|lo

    const int tid = threadIdx.x, lane = tid & 63, wv = tid >> 6;
    const int col = lane & 15, grp = lane >> 4;
    const int wr = wv >> 1, wc = wv & 1;

    // XCD-bijective remap (grid size divisible by 8)
    const int NX = gridDim.x, NB = NX * gridDim.y;
    const int bid = blockIdx.y * NX + blockIdx.x;
    const int bid2 = (bid & 7) * (NB >> 3) + (bid >> 3);
    const int nt = bid2 % NX, mt = bid2 / NX;

    const int proj = (nt * 128) >> 10;                    // 0 for mode 1
    const float* Wsel = proj==0 ? W0 : (proj==1 ? W1 : W2);

    // staging: thread -> row r = tid>>1 (tile-local), 16-float half ch = tid&1
    const int r  = tid >> 1;
    const int ch = tid & 1;
    const float* arow = A    + (size_t)(mt*128 + r)*DM + ch*16;
    const float* brow = Wsel + (size_t)(((nt*128) & 1023) + r)*DM + ch*16;
    // LDS byte addresses for this thread's 2x16B chunks (hi at p=0, lo at p=1)
    const int sw   = (r & 7) << 4;
    const int base = r*128 + ch*32;
    char* aw_hi1 = (char*)Ab + ((base     ) ^ sw);
    char* aw_hi2 = (char*)Ab + ((base + 16) ^ sw);
    char* aw_lo1 = (char*)Ab + ((base + 64) ^ sw);
    char* aw_lo2 = (char*)Ab + ((base + 80) ^ sw);
    char* bw_hi1 = (char*)Bb + ((base     ) ^ sw);
    char* bw_hi2 = (char*)Bb + ((base + 16) ^ sw);
    char* bw_lo1 = (char*)Bb + ((base + 64) ^ sw);
    char* bw_lo2 = (char*)Bb + ((base + 80) ^ sw);

    f32x4 acc[4][4];
    #pragma unroll
    for (int mf=0; mf<4; ++mf)
        #pragma unroll
        for (int nf=0; nf<4; ++nf)
            acc[mf][nf] = (f32x4)0.f;

    for (int kt = 0; kt < 32; ++kt) {
        // ---- load 16 fp32 of A-row + 16 of B-row (issued before barrier)
        float4 fa0 = ((const float4*)(arow + kt*32))[0];
        float4 fa1 = ((const float4*)(arow + kt*32))[1];
        float4 fa2 = ((const float4*)(arow + kt*32))[2];
        float4 fa3 = ((const float4*)(arow + kt*32))[3];
        float4 fb0 = ((const float4*)(brow + kt*32))[0];
        float4 fb1 = ((const float4*)(brow + kt*32))[1];
        float4 fb2 = ((const float4*)(brow + kt*32))[2];
        float4 fb3 = ((const float4*)(brow + kt*32))[3];

        __syncthreads();     // previous step's LDS readers done

        // ---- truncation split + pack + ds_write (A then B)
        {
            const float fe[16] = {fa0.x,fa0.y,fa0.z,fa0.w, fa1.x,fa1.y,fa1.z,fa1.w,
                                  fa2.x,fa2.y,fa2.z,fa2.w, fa3.x,fa3.y,fa3.z,fa3.w};
            unsigned int hp[8], lp[8];
            #pragma unroll
            for (int i = 0; i < 8; ++i) {
                const unsigned int b0 = __float_as_uint(fe[2*i]);
                const unsigned int b1 = __float_as_uint(fe[2*i+1]);
                hp[i] = packtop(b0, b1);
                const float l0 = fe[2*i]   - __uint_as_float(b0 & 0xffff0000u);
                const float l1 = fe[2*i+1] - __uint_as_float(b1 & 0xffff0000u);
                lp[i] = packtop(__float_as_uint(l0), __float_as_uint(l1));
            }
            *(uint4*)aw_hi1 = make_uint4(hp[0],hp[1],hp[2],hp[3]);
            *(uint4*)aw_hi2 = make_uint4(hp[4],hp[5],hp[6],hp[7]);
            *(uint4*)aw_lo1 = make_uint4(lp[0],lp[1],lp[2],lp[3]);
            *(uint4*)aw_lo2 = make_uint4(lp[4],lp[5],lp[6],lp[7]);
        }
        {
            const float fe[16] = {fb0.x,fb0.y,fb0.z,fb0.w, fb1.x,fb1.y,fb1.z,fb1.w,
                                  fb2.x,fb2.y,fb2.z,fb2.w, fb3.x,fb3.y,fb3.z,fb3.w};
            unsigned int hp[8], lp[8];
            #pragma unroll
            for (int i = 0; i < 8; ++i) {
                const unsigned int b0 = __float_as_uint(fe[2*i]);
                const unsigned int b1 = __float_as_uint(fe[2*i+1]);
                hp[i] = packtop(b0, b1);
                const float l0 = fe[2*i]   - __uint_as_float(b0 & 0xffff0000u);
                const float l1 = fe[2*i+1] - __uint_as_float(b1 & 0xffff0000u);
                lp[i] = packtop(__float_as_uint(l0), __float_as_uint(l1));
            }
            *(uint4*)bw_hi1 = make_uint4(hp[0],hp[1],hp[2],hp[3]);
            *(uint4*)bw_hi2 = make_uint4(hp[4],hp[5],hp[6],hp[7]);
            *(uint4*)bw_lo1 = make_uint4(lp[0],lp[1],lp[2],lp[3]);
            *(uint4*)bw_lo2 = make_uint4(lp[4],lp[5],lp[6],lp[7]);
        }

        __syncthreads();     // LDS tile ready

        const char* Ax = (const char*)Ab;
        const char* Bx = (const char*)Bb;
        bf16x8 ah[4], al[4];
        #pragma unroll
        for (int mf = 0; mf < 4; ++mf) {
            const int rl = wr*64 + mf*16 + col;
            const int b0 = rl*128 + grp*16;
            const int s2 = (rl & 7) << 4;
            ah[mf] = *(const bf16x8*)(Ax + (b0 ^ s2));
            al[mf] = *(const bf16x8*)(Ax + ((b0 + 64) ^ s2));
        }
        #pragma unroll
        for (int nf = 0; nf < 4; ++nf) {
            const int rl = wc*64 + nf*16 + col;
            const int b0 = rl*128 + grp*16;
            const int s2 = (rl & 7) << 4;
            bf16x8 bh  = *(const bf16x8*)(Bx + (b0 ^ s2));
            bf16x8 blo = *(const bf16x8*)(Bx + ((b0 + 64) ^ s2));
            #pragma unroll
            for (int mf = 0; mf < 4; ++mf) {
                acc[mf][nf] = __builtin_amdgcn_mfma_f32_16x16x32_bf16(ah[mf], bh,  acc[mf][nf], 0,0,0);
                acc[mf][nf] = __builtin_amdgcn_mfma_f32_16x16x32_bf16(ah[mf], blo, acc[mf][nf], 0,0,0);
                acc[mf][nf] = __builtin_amdgcn_mfma_f32_16x16x32_bf16(al[mf], bh,  acc[mf][nf], 0,0,0);
            }
        }
    }

    // ---- epilogue. C row = m0+wr*64+mf*16+grp*4+i ; C col = n0+wc*64+nf*16+col
    const int m0 = mt*128, n0 = nt*128;
    if (mode == 1) {
        #pragma unroll
        for (int nf = 0; nf < 4; ++nf) {
            const int n = n0 + wc*64 + nf*16 + col;
            const float bn = bo[n];
            #pragma unroll
            for (int mf = 0; mf < 4; ++mf)
                #pragma unroll
                for (int i = 0; i < 4; ++i) {
                    const int tok = m0 + wr*64 + mf*16 + grp*4 + i;
                    outp[(size_t)tok*DM + n] = acc[mf][nf][i] + bn;
                }
        }
    } else {
        const float* bb = proj==0 ? bq : (proj==1 ? bk : bv);
        float* op       = proj==0 ? qo : (proj==1 ? ko : vo);
        const float* pp = proj==0 ? qpos : kpos;
        #pragma unroll
        for (int nf = 0; nf < 4; ++nf) {
            const int n  = n0 + wc*64 + nf*16 + col;
            const int nn = n & 1023;
            const int h  = nn >> 6, dd = nn & 63;
            const float bn = bb[nn];
            if (proj == 2) {
                #pragma unroll
                for (int mf = 0; mf < 4; ++mf)
                    #pragma unroll
                    for (int i = 0; i < 4; ++i) {
                        const int tok = m0 + wr*64 + mf*16 + grp*4 + i;
                        const int b = tok >> 11, sq = tok & 2047;
                        op[(((size_t)(b*HEADS + h))*SEQ + sq)*HDIM + dd] = acc[mf][nf][i] + bn;
                    }
            } else {
                const int plane = dd >> 5;
                const float e = (float)(dd & 30) * (1.0f/32.0f);
                const float invf = exp2f(-L2_10000 * e);
                #pragma unroll
                for (int mf = 0; mf < 4; ++mf)
                    #pragma unroll
                    for (int i = 0; i < 4; ++i) {
                        const int tok = m0 + wr*64 + mf*16 + grp*4 + i;
                        const int b = tok >> 11, sq = tok & 2047;
                        const float pv = pp[((size_t)(b*SEQ + sq))*2 + plane];
                        const float ang = pv * ROPE_SCALE * invf;
                        float s, c;
                        sincosf(ang, &s, &c);
                        const float val = acc[mf][nf][i] + bn;
                        const float prt = __shfl_xor(val, 1);
                        const float res = (dd & 1) ? (prt*s + val*c) : (val*c - prt*s);
                        op[(((size_t)(b*HEADS + h))*SEQ + sq)*HDIM + dd] = res;
                    }
            }
        }
    }
}

// ---------------------------------------------------------------------------
// Kernel: MFMA flash attention (unchanged).
// ---------------------------------------------------------------------------
#define KB 32

__global__ __launch_bounds__(256) void attn_mfma(
    const float* __restrict__ q, const float* __restrict__ k,
    const float* __restrict__ v, float* __restrict__ ao)
{
    const int bh  = blockIdx.y;
    const int qb0 = blockIdx.x * 128;
    const int tid = threadIdx.x;
    const int lane = tid & 63;
    const int wv   = tid >> 6;
    const int col  = lane & 15;
    const int grp  = lane >> 4;

    __shared__ __align__(16) unsigned short Khi[KB][72];
    __shared__ __align__(16) unsigned short Klo[KB][72];
    __shared__ __align__(16) unsigned short Vthi[HDIM][40];
    __shared__ __align__(16) unsigned short Vtlo[HDIM][40];
    __shared__ __align__(16) unsigned short Pb[4][32][40];

    const float* kbase = k + (size_t)bh*SEQ*HDIM;
    const float* vbase = v + (size_t)bh*SEQ*HDIM;

    bf16x8 qhi[2][2], qlo[2][2];
    #pragma unroll
    for (int mf = 0; mf < 2; ++mf)
        #pragma unroll
        for (int ks = 0; ks < 2; ++ks) {
            const float* p = q + ((size_t)bh*SEQ + qb0 + wv*32 + mf*16 + col)*HDIM
                               + ks*32 + grp*8;
            split8(p, qhi[mf][ks], qlo[mf][ks]);
        }

    f32x4 o[2][4];
    #pragma unroll
    for (int mf=0; mf<2; ++mf)
        #pragma unroll
        for (int nf=0; nf<4; ++nf)
            o[mf][nf] = (f32x4)0.f;
    float mrun[2][4], lrun[2][4];
    #pragma unroll
    for (int mf=0; mf<2; ++mf)
        #pragma unroll
        for (int r=0; r<4; ++r) { mrun[mf][r] = -INFINITY; lrun[mf][r] = 0.f; }

    for (int kt = 0; kt < SEQ; kt += KB) {
        __syncthreads();
        {
            const int row = tid >> 3, c0 = (tid & 7) * 8;
            bf16x8 h, l;
            split8(kbase + (size_t)(kt + row)*HDIM + c0, h, l);
            *(bf16x8*)&Khi[row][c0] = h;
            *(bf16x8*)&Klo[row][c0] = l;
        }
        {
            const int key = tid & 31, db = tid >> 5;
            const float* src = vbase + (size_t)(kt + key)*HDIM + db*8;
            float4 f0 = ((const float4*)src)[0];
            float4 f1 = ((const float4*)src)[1];
            float fv[8] = {f0.x,f0.y,f0.z,f0.w,f1.x,f1.y,f1.z,f1.w};
            #pragma unroll
            for (int j = 0; j < 8; ++j) {
                unsigned short hb = f2bf(fv[j]);
                Vthi[db*8+j][key] = hb;
                Vtlo[db*8+j][key] = f2bf(fv[j] - bf2f(hb));
            }
        }
        __syncthreads();

        f32x4 s[2][2];
        #pragma unroll
        for (int mf=0; mf<2; ++mf)
            #pragma unroll
            for (int nf=0; nf<2; ++nf)
                s[mf][nf] = (f32x4)0.f;
        #pragma unroll
        for (int ks = 0; ks < 2; ++ks) {
            bf16x8 kh[2], kl[2];
            #pragma unroll
            for (int nf = 0; nf < 2; ++nf) {
                kh[nf] = *(const bf16x8*)&Khi[nf*16 + col][ks*32 + grp*8];
                kl[nf] = *(const bf16x8*)&Klo[nf*16 + col][ks*32 + grp*8];
            }
            #pragma unroll
            for (int mf = 0; mf < 2; ++mf)
                #pragma unroll
                for (int nf = 0; nf < 2; ++nf) {
                    s[mf][nf] = __builtin_amdgcn_mfma_f32_16x16x32_bf16(qhi[mf][ks], kh[nf], s[mf][nf], 0,0,0);
                    s[mf][nf] = __builtin_amdgcn_mfma_f32_16x16x32_bf16(qlo[mf][ks], kh[nf], s[mf][nf], 0,0,0);
                    s[mf][nf] = __builtin_amdgcn_mfma_f32_16x16x32_bf16(qhi[mf][ks], kl[nf], s[mf][nf], 0,0,0);
                }
        }

        #pragma unroll
        for (int mf=0; mf<2; ++mf)
            #pragma unroll
            for (int nf=0; nf<2; ++nf)
                s[mf][nf] *= 0.125f;

        #pragma unroll
        for (int mf = 0; mf < 2; ++mf) {
            #pragma unroll
            for (int r = 0; r < 4; ++r) {
                float m2 = fmaxf(s[mf][0][r], s[mf][1][r]);
                m2 = fmaxf(m2, __shfl_xor(m2, 1, 16));
                m2 = fmaxf(m2, __shfl_xor(m2, 2, 16));
                m2 = fmaxf(m2, __shfl_xor(m2, 4, 16));
                m2 = fmaxf(m2, __shfl_xor(m2, 8, 16));
                const float mnew = fmaxf(mrun[mf][r], m2);
                const float corr = __expf(mrun[mf][r] - mnew);
                mrun[mf][r] = mnew;
                const float p0 = __expf(s[mf][0][r] - mnew);
                const float p1 = __expf(s[mf][1][r] - mnew);
                float ts = p0 + p1;
                ts += __shfl_xor(ts, 1, 16);
                ts += __shfl_xor(ts, 2, 16);
                ts += __shfl_xor(ts, 4, 16);
                ts += __shfl_xor(ts, 8, 16);
                lrun[mf][r] = lrun[mf][r]*corr + ts;
                #pragma unroll
                for (int nf=0; nf<4; ++nf) o[mf][nf][r] *= corr;
                Pb[wv][mf*16 + grp*4 + r][col]      = f2bf(p0);
                Pb[wv][mf*16 + grp*4 + r][16 + col] = f2bf(p1);
            }
        }

        bf16x8 pa[2];
        #pragma unroll
        for (int mf=0; mf<2; ++mf)
            pa[mf] = *(const bf16x8*)&Pb[wv][mf*16 + col][grp*8];
        #pragma unroll
        for (int nf = 0; nf < 4; ++nf) {
            bf16x8 vh = *(const bf16x8*)&Vthi[nf*16 + col][grp*8];
            bf16x8 vl = *(const bf16x8*)&Vtlo[nf*16 + col][grp*8];
            #pragma unroll
            for (int mf = 0; mf < 2; ++mf) {
                o[mf][nf] = __builtin_amdgcn_mfma_f32_16x16x32_bf16(pa[mf], vh, o[mf][nf], 0,0,0);
                o[mf][nf] = __builtin_amdgcn_mfma_f32_16x16x32_bf16(pa[mf], vl, o[mf][nf], 0,0,0);
            }
        }
    }

    const int b = bh >> 4, h = bh & 15;
    #pragma unroll
    for (int mf = 0; mf < 2; ++mf)
        #pragma unroll
        for (int r = 0; r < 4; ++r) {
            const float inv = 1.0f / lrun[mf][r];
            const int n = qb0 + wv*32 + mf*16 + grp*4 + r;
            float* orow = ao + (((size_t)b*SEQ + n)*HEADS + h)*HDIM;
            #pragma unroll
            for (int nf = 0; nf < 4; ++nf)
                orow[nf*16 + col] = o[mf][nf][r] * inv;
        }
}

// ---------------------------------------------------------------------------
extern "C" void kernel_launch(void* const* d_in, const int* in_sizes, int n_in,
                              void* d_out, int out_size, void* d_ws, size_t ws_size,
                              hipStream_t stream)
{
    const float* x    = (const float*)d_in[0];
    const float* qpos = (const float*)d_in[1];
    const float* kpos = (const float*)d_in[2];
    const float* Wq   = (const float*)d_in[3];
    const float* bq   = (const float*)d_in[4];
    const float* Wk   = (const float*)d_in[5];
    const float* bk   = (const float*)d_in[6];
    const float* Wv   = (const float*)d_in[7];
    const float* bv   = (const float*)d_in[8];
    const float* Wo   = (const float*)d_in[9];
    const float* bo   = (const float*)d_in[10];
    float* out = (float*)d_out;

    // workspace (64 MB): qw/kw/vw fp32 [B*H][N][D] + aw fp32 [tok][1024]
    float* qw = (float*)d_ws;
    float* kw = qw + (size_t)NTOK*DM;
    float* vw = kw + (size_t)NTOK*DM;
    float* aw = vw + (size_t)NTOK*DM;

    gemm_fused<<<dim3(24, 32), 256, 0, stream>>>(
        x, Wq, Wk, Wv, 0, bq, bk, bv, qpos, kpos, qw, kw, vw, nullptr, nullptr);

    attn_mfma<<<dim3(SEQ/128, 2*HEADS), 256, 0, stream>>>(qw, kw, vw, aw);

    gemm_fused<<<dim3(8, 32), 256, 0, stream>>>(
        aw, Wo, nullptr, nullptr, 1, nullptr, nullptr, nullptr, nullptr, nullptr,
        nullptr, nullptr, nullptr, bo, out);
}

// Round 8
// 666.319 us; speedup vs baseline: 1.3166x; 1.0051x over previous
//
#include <hip/hip_runtime.h>
#include <math.h>

// Problem constants (fixed by reference: B=2, N=2048, d_model=1024, H=16, D=64)
#define SEQ   2048
#define DM    1024
#define NTOK  4096      // B*SEQ
#define HEADS 16
#define HDIM  64
#define ROPE_SCALE 0.006135923151542565f   // 2*pi/1024
#define L2_10000   13.287712379549449f     // log2(10000)

typedef __attribute__((ext_vector_type(8))) short bf16x8;
typedef __attribute__((ext_vector_type(4))) unsigned short u16x4;
typedef __attribute__((ext_vector_type(4))) float f32x4;

__device__ __forceinline__ unsigned short f2bf(float f) {
    unsigned int u = __float_as_uint(f);
    return (unsigned short)((u + 0x7FFFu + ((u >> 16) & 1u)) >> 16);
}
__device__ __forceinline__ float bf2f(unsigned short h) {
    return __uint_as_float(((unsigned int)h) << 16);
}

__device__ __forceinline__ void split8(const float* __restrict__ src, bf16x8& h, bf16x8& l) {
    float4 f0 = ((const float4*)src)[0];
    float4 f1 = ((const float4*)src)[1];
    float fv[8] = {f0.x,f0.y,f0.z,f0.w,f1.x,f1.y,f1.z,f1.w};
    #pragma unroll
    for (int j = 0; j < 8; ++j) {
        unsigned short hb = f2bf(fv[j]);
        h[j] = (short)hb;
        l[j] = (short)f2bf(fv[j] - bf2f(hb));
    }
}

__device__ __forceinline__ void gload16(const void* g, void* l) {
    __builtin_amdgcn_global_load_lds(
        (const __attribute__((address_space(1))) unsigned int*)g,
        (__attribute__((address_space(3))) unsigned int*)l, 16, 0, 0);
}

// ---------------------------------------------------------------------------
// Pack fp32 [R][1024] -> swizzled bf16 hi|lo tiles of 128 rows x 32 k.
// Tile (mt,kt) is 16384 B at (mt*32+kt)*8192 shorts. In-tile byte offset of
// (r,k,part p) = (r*128 + p*64 + k*2) ^ ((r&7)<<4).
// ---------------------------------------------------------------------------
__global__ __launch_bounds__(256) void pack_swz(
    const float* __restrict__ src, unsigned short* __restrict__ dst)
{
    const int idx = blockIdx.x*256 + threadIdx.x;   // one thread per 8 elements
    const int e = idx * 8;
    const int r = e >> 10, k0 = e & 1023;
    bf16x8 h, l;
    split8(src + (size_t)r*DM + k0, h, l);
    const int mt = r >> 7, rl = r & 127;
    const int kt = k0 >> 5, kl = k0 & 31;
    char* tb = (char*)(dst + ((size_t)(mt*32 + kt))*8192);
    const int sw = (rl & 7) << 4;
    *(bf16x8*)(tb + ((rl*128 + kl*2) ^ sw))      = h;
    *(bf16x8*)(tb + ((rl*128 + 64 + kl*2) ^ sw)) = l;
}

// Fused [Wq;Wk;Wv] variant: rows 0..3071, source row (r&1023) of W[r>>10].
__global__ __launch_bounds__(256) void pack_swz3(
    const float* __restrict__ Wq, const float* __restrict__ Wk,
    const float* __restrict__ Wv, unsigned short* __restrict__ dst)
{
    const int idx = blockIdx.x*256 + threadIdx.x;
    const int e = idx * 8;
    const int r = e >> 10, k0 = e & 1023;
    const int proj = r >> 10;
    const float* W = proj==0 ? Wq : (proj==1 ? Wk : Wv);
    bf16x8 h, l;
    split8(W + (size_t)(r & 1023)*DM + k0, h, l);
    const int mt = r >> 7, rl = r & 127;
    const int kt = k0 >> 5, kl = k0 & 31;
    char* tb = (char*)(dst + ((size_t)(mt*32 + kt))*8192);
    const int sw = (rl & 7) << 4;
    *(bf16x8*)(tb + ((rl*128 + kl*2) ^ sw))      = h;
    *(bf16x8*)(tb + ((rl*128 + 64 + kl*2) ^ sw)) = l;
}

// ---------------------------------------------------------------------------
// Split-bf16 MFMA GEMM (r6 structure: single-buffered 32 KB LDS, 2 barriers
// per K-step, global_load_lds staging, XCD-chunked remap, 3 MFMAs/product).
// mode 0: fused qkv (N=3072): bias + 2D RoPE; OUTPUT = packed bf16 hi|lo:
//   q,k -> [bh][plane][N][D] ushort ; v -> TRANSPOSED [bh][plane][D][N].
// mode 1: out-proj (N=1024): bias, fp32 row-major [tok][1024].
// ---------------------------------------------------------------------------
__global__ __launch_bounds__(256, 3) void gemm_mfma(
    const unsigned short* __restrict__ Ap, const unsigned short* __restrict__ Bp,
    const int mode,
    const float* __restrict__ bq, const float* __restrict__ bk,
    const float* __restrict__ bv,
    const float* __restrict__ qpos, const float* __restrict__ kpos,
    unsigned short* __restrict__ qo, unsigned short* __restrict__ ko,
    unsigned short* __restrict__ vo,
    const float* __restrict__ bo, float* __restrict__ outp)
{
    __shared__ __align__(16) unsigned short Ab[8192];   // 16 KB (hi|lo tile)
    __shared__ __align__(16) unsigned short Bb[8192];   // 16 KB

    const int tid = threadIdx.x, lane = tid & 63, wv = tid >> 6;
    const int col = lane & 15, grp = lane >> 4;
    const int wr = wv >> 1, wc = wv & 1;

    // XCD-bijective remap (grid size divisible by 8)
    const int NX = gridDim.x, NB = NX * gridDim.y;
    const int bid = blockIdx.y * NX + blockIdx.x;
    const int bid2 = (bid & 7) * (NB >> 3) + (bid >> 3);
    const int nt = bid2 % NX, mt = bid2 / NX;

    f32x4 acc[4][4];
    #pragma unroll
    for (int mf=0; mf<4; ++mf)
        #pragma unroll
        for (int nf=0; nf<4; ++nf)
            acc[mf][nf] = (f32x4)0.f;

    for (int kt = 0; kt < 32; ++kt) {
        __syncthreads();     // previous step's readers done
        {   // stage 16 KB A + 16 KB B (linear; pre-swizzled in global)
            const char* ga = (const char*)Ap + ((size_t)(mt*32 + kt))*16384;
            const char* gb = (const char*)Bp + ((size_t)(nt*32 + kt))*16384;
            #pragma unroll
            for (int rep = 0; rep < 4; ++rep) {
                const int o = wv*4096 + rep*1024;
                gload16(ga + o + lane*16, (char*)Ab + o);
                gload16(gb + o + lane*16, (char*)Bb + o);
            }
        }
        __syncthreads();     // compiler drains vmcnt(0): tile ready
        const char* A = (const char*)Ab;
        const char* B = (const char*)Bb;
        bf16x8 ah[4], al[4];
        #pragma unroll
        for (int mf = 0; mf < 4; ++mf) {
            const int rl = wr*64 + mf*16 + col;
            const int b0 = rl*128 + grp*16;
            const int sw = (rl & 7) << 4;
            ah[mf] = *(const bf16x8*)(A + (b0 ^ sw));
            al[mf] = *(const bf16x8*)(A + ((b0 + 64) ^ sw));
        }
        #pragma unroll
        for (int nf = 0; nf < 4; ++nf) {
            const int rl = wc*64 + nf*16 + col;
            const int b0 = rl*128 + grp*16;
            const int sw = (rl & 7) << 4;
            bf16x8 bh  = *(const bf16x8*)(B + (b0 ^ sw));
            bf16x8 blo = *(const bf16x8*)(B + ((b0 + 64) ^ sw));
            #pragma unroll
            for (int mf = 0; mf < 4; ++mf) {
                acc[mf][nf] = __builtin_amdgcn_mfma_f32_16x16x32_bf16(ah[mf], bh,  acc[mf][nf], 0,0,0);
                acc[mf][nf] = __builtin_amdgcn_mfma_f32_16x16x32_bf16(ah[mf], blo, acc[mf][nf], 0,0,0);
                acc[mf][nf] = __builtin_amdgcn_mfma_f32_16x16x32_bf16(al[mf], bh,  acc[mf][nf], 0,0,0);
            }
        }
    }

    // ---- epilogue. C row = m0+wr*64+mf*16+grp*4+i ; C col = n0+wc*64+nf*16+col
    const int m0 = mt*128, n0 = nt*128;
    if (mode == 1) {
        #pragma unroll
        for (int nf = 0; nf < 4; ++nf) {
            const int n = n0 + wc*64 + nf*16 + col;
            const float bn = bo[n];
            #pragma unroll
            for (int mf = 0; mf < 4; ++mf)
                #pragma unroll
                for (int i = 0; i < 4; ++i) {
                    const int tok = m0 + wr*64 + mf*16 + grp*4 + i;
                    outp[(size_t)tok*DM + n] = acc[mf][nf][i] + bn;
                }
        }
    } else {
        const int proj = n0 >> 10;              // whole block is one projection
        const float* bb = proj==0 ? bq : (proj==1 ? bk : bv);
        unsigned short* op = proj==0 ? qo : (proj==1 ? ko : vo);
        const float* pp = proj==0 ? qpos : kpos;
        #pragma unroll
        for (int nf = 0; nf < 4; ++nf) {
            const int n  = n0 + wc*64 + nf*16 + col;
            const int nn = n & 1023;
            const int h  = nn >> 6, dd = nn & 63;
            const float bn = bb[nn];
            if (proj == 2) {
                // v: packed transposed [bh][pl][D][N]; 4 consecutive sq -> u16x4
                #pragma unroll
                for (int mf = 0; mf < 4; ++mf) {
                    const int tok0 = m0 + wr*64 + mf*16 + grp*4;
                    const int b = tok0 >> 11, sq0 = tok0 & 2047;
                    u16x4 h4, l4;
                    #pragma unroll
                    for (int i = 0; i < 4; ++i) {
                        const float val = acc[mf][nf][i] + bn;
                        unsigned short hb = f2bf(val);
                        h4[i] = hb;
                        l4[i] = f2bf(val - bf2f(hb));
                    }
                    const int bh2 = (b*HEADS + h)*2;
                    *(u16x4*)(op + ((size_t)(bh2+0)*HDIM + dd)*SEQ + sq0) = h4;
                    *(u16x4*)(op + ((size_t)(bh2+1)*HDIM + dd)*SEQ + sq0) = l4;
                }
            } else {
                // q,k: RoPE then packed [bh][pl][N][D]
                const int plane = dd >> 5;
                const float e = (float)(dd & 30) * (1.0f/32.0f);
                const float invf = exp2f(-L2_10000 * e);
                #pragma unroll
                for (int mf = 0; mf < 4; ++mf)
                    #pragma unroll
                    for (int i = 0; i < 4; ++i) {
                        const int tok = m0 + wr*64 + mf*16 + grp*4 + i;
                        const int b = tok >> 11, sq = tok & 2047;
                        const float pv = pp[((size_t)(b*SEQ + sq))*2 + plane];
                        const float ang = pv * ROPE_SCALE * invf;
                        float s, c;
                        sincosf(ang, &s, &c);
                        const float val = acc[mf][nf][i] + bn;
                        const float prt = __shfl_xor(val, 1);
                        const float res = (dd & 1) ? (prt*s + val*c) : (val*c - prt*s);
                        unsigned short hb = f2bf(res);
                        unsigned short lb = f2bf(res - bf2f(hb));
                        const int bh2 = (b*HEADS + h)*2;
                        op[((size_t)(bh2+0)*SEQ + sq)*HDIM + dd] = hb;
                        op[((size_t)(bh2+1)*SEQ + sq)*HDIM + dd] = lb;
                    }
            }
        }
    }
}

// ---------------------------------------------------------------------------
// MFMA flash attention reading PRE-SPLIT packed bf16 hi|lo q/k/v.
// q,k: [bh][pl][N][D]; v: [bh][pl][D][N] (pre-transposed).
// Staging is pure 16B copy; no VALU split, no in-kernel transpose.
// ---------------------------------------------------------------------------
#define KB 32

__global__ __launch_bounds__(256) void attn_mfma(
    const unsigned short* __restrict__ q, const unsigned short* __restrict__ k,
    const unsigned short* __restrict__ v, float* __restrict__ ao)
{
    const int bh  = blockIdx.y;
    const int qb0 = blockIdx.x * 128;
    const int tid = threadIdx.x;
    const int lane = tid & 63;
    const int wv   = tid >> 6;
    const int col  = lane & 15;
    const int grp  = lane >> 4;

    __shared__ __align__(16) unsigned short Khi[KB][72];
    __shared__ __align__(16) unsigned short Klo[KB][72];
    __shared__ __align__(16) unsigned short Vthi[HDIM][40];
    __shared__ __align__(16) unsigned short Vtlo[HDIM][40];
    __shared__ __align__(16) unsigned short Pb[4][32][40];

    const unsigned short* kh_g = k + (size_t)(bh*2)*SEQ*HDIM;
    const unsigned short* kl_g = kh_g + (size_t)SEQ*HDIM;
    const unsigned short* vh_g = v + (size_t)(bh*2)*HDIM*SEQ;
    const unsigned short* vl_g = vh_g + (size_t)HDIM*SEQ;

    // ---- Q fragments: direct packed loads (A-layout: row=col, k=ks*32+grp*8)
    bf16x8 qhi[2][2], qlo[2][2];
    {
        const unsigned short* qh_g = q + (size_t)(bh*2)*SEQ*HDIM;
        const unsigned short* ql_g = qh_g + (size_t)SEQ*HDIM;
        #pragma unroll
        for (int mf = 0; mf < 2; ++mf)
            #pragma unroll
            for (int ks = 0; ks < 2; ++ks) {
                const size_t off = (size_t)(qb0 + wv*32 + mf*16 + col)*HDIM + ks*32 + grp*8;
                qhi[mf][ks] = *(const bf16x8*)(qh_g + off);
                qlo[mf][ks] = *(const bf16x8*)(ql_g + off);
            }
    }

    f32x4 o[2][4];
    #pragma unroll
    for (int mf=0; mf<2; ++mf)
        #pragma unroll
        for (int nf=0; nf<4; ++nf)
            o[mf][nf] = (f32x4)0.f;
    float mrun[2][4], lrun[2][4];
    #pragma unroll
    for (int mf=0; mf<2; ++mf)
        #pragma unroll
        for (int r=0; r<4; ++r) { mrun[mf][r] = -INFINITY; lrun[mf][r] = 0.f; }

    for (int kt = 0; kt < SEQ; kt += KB) {
        __syncthreads();
        {   // K tile: pure copy (row = tid>>3, 8 dims at (tid&7)*8)
            const int row = tid >> 3, c0 = (tid & 7) * 8;
            const size_t off = (size_t)(kt + row)*HDIM + c0;
            *(bf16x8*)&Khi[row][c0] = *(const bf16x8*)(kh_g + off);
            *(bf16x8*)&Klo[row][c0] = *(const bf16x8*)(kl_g + off);
        }
        {   // V^T tile: pure copy (d-row = tid>>2, 8 keys at (tid&3)*8)
            const int d = tid >> 2, c = (tid & 3) * 8;
            const size_t off = (size_t)d*SEQ + kt + c;
            *(bf16x8*)&Vthi[d][c] = *(const bf16x8*)(vh_g + off);
            *(bf16x8*)&Vtlo[d][c] = *(const bf16x8*)(vl_g + off);
        }
        __syncthreads();

        f32x4 s[2][2];
        #pragma unroll
        for (int mf=0; mf<2; ++mf)
            #pragma unroll
            for (int nf=0; nf<2; ++nf)
                s[mf][nf] = (f32x4)0.f;
        #pragma unroll
        for (int ks = 0; ks < 2; ++ks) {
            bf16x8 kh[2], kl[2];
            #pragma unroll
            for (int nf = 0; nf < 2; ++nf) {
                kh[nf] = *(const bf16x8*)&Khi[nf*16 + col][ks*32 + grp*8];
                kl[nf] = *(const bf16x8*)&Klo[nf*16 + col][ks*32 + grp*8];
            }
            #pragma unroll
            for (int mf = 0; mf < 2; ++mf)
                #pragma unroll
                for (int nf = 0; nf < 2; ++nf) {
                    s[mf][nf] = __builtin_amdgcn_mfma_f32_16x16x32_bf16(qhi[mf][ks], kh[nf], s[mf][nf], 0,0,0);
                    s[mf][nf] = __builtin_amdgcn_mfma_f32_16x16x32_bf16(qlo[mf][ks], kh[nf], s[mf][nf], 0,0,0);
                    s[mf][nf] = __builtin_amdgcn_mfma_f32_16x16x32_bf16(qhi[mf][ks], kl[nf], s[mf][nf], 0,0,0);
                }
        }

        #pragma unroll
        for (int mf=0; mf<2; ++mf)
            #pragma unroll
            for (int nf=0; nf<2; ++nf)
                s[mf][nf] *= 0.125f;

        #pragma unroll
        for (int mf = 0; mf < 2; ++mf) {
            #pragma unroll
            for (int r = 0; r < 4; ++r) {
                float m2 = fmaxf(s[mf][0][r], s[mf][1][r]);
                m2 = fmaxf(m2, __shfl_xor(m2, 1, 16));
                m2 = fmaxf(m2, __shfl_xor(m2, 2, 16));
                m2 = fmaxf(m2, __shfl_xor(m2, 4, 16));
                m2 = fmaxf(m2, __shfl_xor(m2, 8, 16));
                const float mnew = fmaxf(mrun[mf][r], m2);
                const float corr = __expf(mrun[mf][r] - mnew);
                mrun[mf][r] = mnew;
                const float p0 = __expf(s[mf][0][r] - mnew);
                const float p1 = __expf(s[mf][1][r] - mnew);
                float ts = p0 + p1;
                ts += __shfl_xor(ts, 1, 16);
                ts += __shfl_xor(ts, 2, 16);
                ts += __shfl_xor(ts, 4, 16);
                ts += __shfl_xor(ts, 8, 16);
                lrun[mf][r] = lrun[mf][r]*corr + ts;
                #pragma unroll
                for (int nf=0; nf<4; ++nf) o[mf][nf][r] *= corr;
                Pb[wv][mf*16 + grp*4 + r][col]      = f2bf(p0);
                Pb[wv][mf*16 + grp*4 + r][16 + col] = f2bf(p1);
            }
        }

        bf16x8 pa[2];
        #pragma unroll
        for (int mf=0; mf<2; ++mf)
            pa[mf] = *(const bf16x8*)&Pb[wv][mf*16 + col][grp*8];
        #pragma unroll
        for (int nf = 0; nf < 4; ++nf) {
            bf16x8 vh = *(const bf16x8*)&Vthi[nf*16 + col][grp*8];
            bf16x8 vl = *(const bf16x8*)&Vtlo[nf*16 + col][grp*8];
            #pragma unroll
            for (int mf = 0; mf < 2; ++mf) {
                o[mf][nf] = __builtin_amdgcn_mfma_f32_16x16x32_bf16(pa[mf], vh, o[mf][nf], 0,0,0);
                o[mf][nf] = __builtin_amdgcn_mfma_f32_16x16x32_bf16(pa[mf], vl, o[mf][nf], 0,0,0);
            }
        }
    }

    const int b = bh >> 4, h = bh & 15;
    #pragma unroll
    for (int mf = 0; mf < 2; ++mf)
        #pragma unroll
        for (int r = 0; r < 4; ++r) {
            const float inv = 1.0f / lrun[mf][r];
            const int n = qb0 + wv*32 + mf*16 + grp*4 + r;
            float* orow = ao + (((size_t)b*SEQ + n)*HEADS + h)*HDIM;
            #pragma unroll
            for (int nf = 0; nf < 4; ++nf)
                orow[nf*16 + col] = o[mf][nf][r] * inv;
        }
}

// ---------------------------------------------------------------------------
extern "C" void kernel_launch(void* const* d_in, const int* in_sizes, int n_in,
                              void* d_out, int out_size, void* d_ws, size_t ws_size,
                              hipStream_t stream)
{
    const float* x    = (const float*)d_in[0];
    const float* qpos = (const float*)d_in[1];
    const float* kpos = (const float*)d_in[2];
    const float* Wq   = (const float*)d_in[3];
    const float* bq   = (const float*)d_in[4];
    const float* Wk   = (const float*)d_in[5];
    const float* bk   = (const float*)d_in[6];
    const float* Wv   = (const float*)d_in[7];
    const float* bv   = (const float*)d_in[8];
    const float* Wo   = (const float*)d_in[9];
    const float* bo   = (const float*)d_in[10];
    float* out = (float*)d_out;

    // workspace (80 MB), with overlays:
    //   qp 16 MB | kp 16 MB | vp 16 MB | X/aw 16 MB | Wqkvp 12 MB + Wop 4 MB
    //   X (packed x) used by gemm0; aw (fp32 attn out) overlays X afterwards.
    //   packed attn-out (Ap2) overlays qp (dead after attn).
    unsigned short* qp = (unsigned short*)d_ws;                  // 8M ushorts
    unsigned short* kp = qp + (size_t)8388608;
    unsigned short* vp = kp + (size_t)8388608;
    unsigned short* Xp = vp + (size_t)8388608;                   // packed x
    float*          aw = (float*)Xp;                             // overlay
    unsigned short* Wqkvp = Xp + (size_t)8388608;
    unsigned short* Wop   = Wqkvp + (size_t)6291456;
    unsigned short* Ap2   = qp;                                  // overlay

    pack_swz <<<2048, 256, 0, stream>>>(x, Xp);
    pack_swz3<<<1536, 256, 0, stream>>>(Wq, Wk, Wv, Wqkvp);
    pack_swz <<< 512, 256, 0, stream>>>(Wo, Wop);

    gemm_mfma<<<dim3(24, 32), 256, 0, stream>>>(
        Xp, Wqkvp, 0, bq, bk, bv, qpos, kpos, qp, kp, vp, nullptr, nullptr);

    attn_mfma<<<dim3(SEQ/128, 2*HEADS), 256, 0, stream>>>(qp, kp, vp, aw);

    pack_swz <<<2048, 256, 0, stream>>>(aw, Ap2);

    gemm_mfma<<<dim3(8, 32), 256, 0, stream>>>(
        Ap2, Wop, 1, nullptr, nullptr, nullptr, nullptr, nullptr,
        nullptr, nullptr, nullptr, bo, out);
}